// Round 4
// baseline (496.351 us; speedup 1.0000x reference)
//
#include <hip/hip_runtime.h>
#include <hip/hip_bf16.h>

typedef __hip_bfloat16 bf16;
typedef __attribute__((ext_vector_type(8))) __bf16 bf16x8;
typedef __attribute__((ext_vector_type(4))) float f32x4;

constexpr int TT = 2048;   // sequence length
constexpr int HD = 2048;   // hidden dim
constexpr int VD = 4096;   // value dim
constexpr int KD = 128;    // key dim per head
constexpr int NH = 16;     // heads
constexpr int DH = 256;    // head dim of v
constexpr float K_SCALING = 0.08838834764831845f;  // 128^-0.5

__device__ __forceinline__ bf16 f2bf(float x) { return __float2bfloat16(x); }
__device__ __forceinline__ unsigned short f2bfu(float x) {
    bf16 b = __float2bfloat16(x);
    return *reinterpret_cast<unsigned short*>(&b);
}

// ---------------------------------------------------------------------------
// f32 -> bf16 linear convert (4 elems/thread)
// ---------------------------------------------------------------------------
__global__ __launch_bounds__(256) void f32_to_bf16_k(const float* __restrict__ in,
                                                     bf16* __restrict__ outb, int n) {
    int i = (blockIdx.x * 256 + threadIdx.x) * 4;
    if (i >= n) return;
    float4 v = *(const float4*)(in + i);
    bf16 tmp[4] = {f2bf(v.x), f2bf(v.y), f2bf(v.z), f2bf(v.w)};
    *(uint2*)(outb + i) = *(const uint2*)tmp;  // 8B store
}

// ---------------------------------------------------------------------------
// W[R][C] f32 -> WT[C][R] bf16  (32x32 LDS tile transpose)
// ---------------------------------------------------------------------------
__global__ __launch_bounds__(256) void transpose_tb_k(const float* __restrict__ W,
                                                      bf16* __restrict__ WT, int R, int C) {
    __shared__ float tile[32][33];
    const int tx = threadIdx.x & 31, ty = threadIdx.x >> 5;  // 32 x 8
    const int x = blockIdx.x * 32 + tx;
    const int y0 = blockIdx.y * 32;
#pragma unroll
    for (int j = 0; j < 4; ++j)
        tile[ty + j * 8][tx] = W[(size_t)(y0 + ty + j * 8) * C + x];
    __syncthreads();
    const int xt = y0 + tx;          // WT col (= W row)
    const int yt0 = blockIdx.x * 32; // WT row block (= W col)
#pragma unroll
    for (int j = 0; j < 4; ++j)
        WT[(size_t)(yt0 + ty + j * 8) * R + xt] = f2bf(tile[tx][ty + j * 8]);
}

// ---------------------------------------------------------------------------
// bf16 transpose: in[T][VD] -> out[VD][T], 64x64 LDS tiles, b128 in/out
// ---------------------------------------------------------------------------
__global__ __launch_bounds__(256) void transpose_bf16_k(const bf16* __restrict__ in,
                                                        bf16* __restrict__ outb) {
    __shared__ unsigned short sT[64 * 72];  // stride 72 halves (144B, b128-aligned)
    const int tid = threadIdx.x;
    const int x0 = blockIdx.x * 64;  // d
    const int y0 = blockIdx.y * 64;  // t
    {
        const int lt = tid >> 2;           // 0..63 (t local)
        const int c0 = (tid & 3) << 4;     // 0,16,32,48 (d local)
        unsigned short e[16];
        *(bf16x8*)&e[0] = *(const bf16x8*)&in[(size_t)(y0 + lt) * VD + x0 + c0];
        *(bf16x8*)&e[8] = *(const bf16x8*)&in[(size_t)(y0 + lt) * VD + x0 + c0 + 8];
#pragma unroll
        for (int i = 0; i < 16; ++i) {
            const int c = c0 + i;
            sT[c * 72 + (lt ^ (((c >> 3) & 7) << 3))] = e[i];
        }
    }
    __syncthreads();
    {
        const int c = tid >> 2;            // 0..63 (d local)
        const int r0 = (tid & 3) << 4;     // 0,16,32,48 (t local)
        const int xs = ((c >> 3) & 7) << 3;
#pragma unroll
        for (int s2 = 0; s2 < 16; s2 += 8) {
            bf16x8 v = *(const bf16x8*)&sT[c * 72 + ((r0 + s2) ^ xs)];
            *(bf16x8*)&outb[(size_t)(x0 + c) * TT + y0 + r0 + s2] = v;
        }
    }
}

// ---------------------------------------------------------------------------
// Fused QKVG GEMM, 8-phase 256x256 schedule.
// C[2048,12288] = hb[2048,2048] @ Wcat[12288,2048]^T
// N-segments: [0,2048)=Q(rope) [2048,4096)=K(rope*scale) [4096,8192)=V [8192,12288)=G(silu)
// 8 waves (2M x 4N), BK=64, dbuf 128KiB LDS, counted vmcnt(6), XOR-swizzled LDS.
// ---------------------------------------------------------------------------
#define GLL(gptr, lptr) __builtin_amdgcn_global_load_lds( \
    (const __attribute__((address_space(1))) void*)(gptr), \
    (__attribute__((address_space(3))) void*)(lptr), 16, 0, 0)

#define STAGE_A(nb, qm, k1) \
    GLL(gA0 + (size_t)((qm) * 64) * HD + (k1), sA + (nb) + (qm) * 4096 + w * 512); \
    GLL(gA0 + (size_t)((qm) * 64 + 128) * HD + (k1), sA + (nb) + (qm) * 4096 + 8192 + w * 512)

#define STAGE_B(nb, qn, k1) \
    GLL(gB0 + (size_t)((qn) * 32) * HD + (k1), sB + (nb) + (qn) * 2048 + (w & 3) * 512 + (w >> 2) * 4096); \
    GLL(gB0 + (size_t)((qn) * 32 + 128) * HD + (k1), sB + (nb) + (qn) * 2048 + 8192 + (w & 3) * 512 + (w >> 2) * 4096)

#define WAIT6 asm volatile("s_waitcnt vmcnt(6)" ::: "memory")
#define WAIT0V asm volatile("s_waitcnt vmcnt(0)" ::: "memory")
#define MEMF asm volatile("" ::: "memory")
#define BAR __builtin_amdgcn_s_barrier()

#define QUAD(cb, qm, qn) { \
    bf16x8 a_[4][2], b_[2][2]; \
    _Pragma("unroll") for (int mi = 0; mi < 4; ++mi) { \
        const int r_ = wr * 128 + (qm) * 64 + mi * 16 + lr; \
        _Pragma("unroll") for (int ks = 0; ks < 2; ++ks) \
            a_[mi][ks] = *(const bf16x8*)&sA[(cb) + r_ * 64 + (((ks * 4 + g) ^ (lr & 7)) << 3)]; \
    } \
    _Pragma("unroll") for (int ni = 0; ni < 2; ++ni) { \
        const int n_ = wcn * 64 + (qn) * 32 + ni * 16 + lr; \
        _Pragma("unroll") for (int ks = 0; ks < 2; ++ks) \
            b_[ni][ks] = *(const bf16x8*)&sB[(cb) + n_ * 64 + (((ks * 4 + g) ^ (lr & 7)) << 3)]; \
    } \
    __builtin_amdgcn_s_setprio(1); \
    _Pragma("unroll") for (int mi = 0; mi < 4; ++mi) \
        _Pragma("unroll") for (int ni = 0; ni < 2; ++ni) \
            _Pragma("unroll") for (int ks = 0; ks < 2; ++ks) \
                acc[(qm) * 4 + mi][(qn) * 2 + ni] = __builtin_amdgcn_mfma_f32_16x16x32_bf16( \
                    a_[mi][ks], b_[ni][ks], acc[(qm) * 4 + mi][(qn) * 2 + ni], 0, 0, 0); \
    __builtin_amdgcn_s_setprio(0); }

__global__ __launch_bounds__(512, 2) void gemm_qkvg_k(
    const bf16* __restrict__ Ag, const bf16* __restrict__ Bg,
    const float* __restrict__ bq, const float* __restrict__ bk,
    const float* __restrict__ bvp, const float* __restrict__ bg,
    const float* __restrict__ sinT, const float* __restrict__ cosT,
    bf16* __restrict__ qr, bf16* __restrict__ kr,
    bf16* __restrict__ vtmp, bf16* __restrict__ sg)
{
    __shared__ unsigned short sA[2 * 256 * 64];  // 64 KB
    __shared__ unsigned short sB[2 * 256 * 64];  // 64 KB

    const int tid = threadIdx.x;
    const int lane = tid & 63;
    const int w = tid >> 6;        // 0..7
    const int wr = w >> 2;         // 0..1  M half
    const int wcn = w & 3;         // 0..3  N quarter
    const int lr = lane & 15;
    const int g = lane >> 4;

    // XCD-aware swizzle: 384 blocks, 48/XCD
    const int flat = blockIdx.x;
    const int swz = (flat & 7) * 48 + (flat >> 3);
    const int brow = (swz & 7) * 256;
    const int by = swz >> 3;          // 0..47
    const int bcol = by * 256;

    // staging per-lane source (inverse-swizzled col-block so LDS reads can XOR)
    const int srow = lane >> 3;             // row within 8-row wave chunk
    const int sblk = (lane & 7) ^ srow;     // swizzled 16B col-block
    const bf16* gA0 = Ag + (size_t)(brow + w * 8 + srow) * HD + sblk * 8;
    const bf16* gB0 = Bg + (size_t)(bcol + (w & 3) * 8 + (w >> 2) * 64 + srow) * HD + sblk * 8;

    f32x4 acc[8][4] = {};

    // prologue: stage tile 0 into buf 0 (pair order A0,B0,A1,B1)
    STAGE_A(0, 0, 0);
    STAGE_B(0, 0, 0);
    STAGE_A(0, 1, 0);
    STAGE_B(0, 1, 0);

    constexpr int NT = HD / 64;  // 32
    for (int t = 0; t < NT - 1; ++t) {
        const int cb = (t & 1) * 16384;
        const int nb = 16384 - cb;
        const int k1 = (t + 1) * 64;
        // phase 0
        STAGE_A(nb, 0, k1);
        WAIT6; BAR; MEMF;
        QUAD(cb, 0, 0);
        MEMF; BAR;
        // phase 1
        STAGE_B(nb, 0, k1);
        WAIT6; BAR; MEMF;
        QUAD(cb, 1, 0);
        MEMF; BAR;
        // phase 2
        STAGE_A(nb, 1, k1);
        WAIT6; BAR; MEMF;
        QUAD(cb, 1, 1);
        MEMF; BAR;
        // phase 3
        STAGE_B(nb, 1, k1);
        WAIT6; BAR; MEMF;
        QUAD(cb, 0, 1);
        MEMF; BAR;
    }
    // last tile: drain once, no staging
    WAIT0V; BAR; MEMF;
    {
        const int cb = ((NT - 1) & 1) * 16384;
        QUAD(cb, 0, 0);
        QUAD(cb, 1, 0);
        QUAD(cb, 1, 1);
        QUAD(cb, 0, 1);
    }

    // ---- epilogue ----
#pragma unroll
    for (int M = 0; M < 8; ++M) {
        const int row = brow + wr * 128 + (M >> 2) * 64 + (M & 3) * 16 + g * 4;
#pragma unroll
        for (int N = 0; N < 4; ++N) {
            const int ncol = bcol + wcn * 64 + (N >> 1) * 32 + (N & 1) * 16 + lr;
            if (by < 16) {
                // Q or K with fused RoPE
                const bool isK = (by >= 8);
                const int col = ncol - (isK ? 2048 : 0);
                const float bvv = (isK ? bk : bq)[col];
                const float scale = isK ? K_SCALING : 1.f;
                bf16* outb = isK ? kr : qr;
                const int d = col & (KD - 1);
#pragma unroll
                for (int r = 0; r < 4; ++r) {
                    float v = (acc[M][N][r] + bvv) * scale;
                    float o = __shfl_xor(v, 1);
                    float rot = (col & 1) ? o : -o;
                    outb[(size_t)(row + r) * HD + col] =
                        f2bf(v * cosT[(row + r) * KD + d] + rot * sinT[(row + r) * KD + d]);
                }
            } else if (by < 32) {
                const int col = ncol - 4096;
                const float bvv = bvp[col];
#pragma unroll
                for (int r = 0; r < 4; ++r)
                    vtmp[(size_t)(row + r) * VD + col] = f2bf(acc[M][N][r] + bvv);
            } else {
                const int col = ncol - 8192;
                const float bvv = bg[col];
#pragma unroll
                for (int r = 0; r < 4; ++r) {
                    float v = acc[M][N][r] + bvv;
                    sg[(size_t)(row + r) * VD + col] = f2bf(v / (1.f + __expf(-v)));
                }
            }
        }
    }
}

// ---------------------------------------------------------------------------
// Output GEMM: out[2048,2048] = gated[2048,4096] @ WoT[2048,4096]^T + bo
// 128x128 tile, 4 waves, BK=32 (m97 structure; 256 blocks)
// ---------------------------------------------------------------------------
__global__ __launch_bounds__(256) void gemm_out_k(
    const bf16* __restrict__ Ag, const bf16* __restrict__ Bg,
    const float* __restrict__ bias, float* __restrict__ outf)
{
    __shared__ unsigned short sOA[128 * 32];
    __shared__ unsigned short sOB[128 * 32];

    const int flat = blockIdx.x;
    const int swz = (flat & 7) * 32 + (flat >> 3);
    const int brow = (swz & 15) * 128;
    const int bcol = (swz >> 4) * 128;

    const int tid = threadIdx.x;
    const int lane = tid & 63;
    const int wid = tid >> 6;
    const int wr = wid >> 1, wc = wid & 1;

    f32x4 acc[4][4] = {};

    const int lr = lane & 15;
    const int lk = (lane >> 4) << 3;
    const int r0 = tid >> 2;
    const int c0 = (tid & 3) << 3;
    const int ldsw = (tid & 192) << 3;

    for (int k0 = 0; k0 < VD; k0 += 32) {
        const bf16* gA = Ag + (size_t)(brow + r0) * VD + k0 + c0;
        const bf16* gB = Bg + (size_t)(bcol + r0) * VD + k0 + c0;
        GLL(gA, sOA + ldsw);
        GLL(gB, sOB + ldsw);
        GLL(gA + 64 * VD, sOA + 2048 + ldsw);
        GLL(gB + 64 * VD, sOB + 2048 + ldsw);
        __syncthreads();

        bf16x8 af[4], bv[4];
#pragma unroll
        for (int mi = 0; mi < 4; ++mi)
            af[mi] = *(const bf16x8*)&sOA[(wr * 64 + mi * 16 + lr) * 32 + lk];
#pragma unroll
        for (int ni = 0; ni < 4; ++ni)
            bv[ni] = *(const bf16x8*)&sOB[(wc * 64 + ni * 16 + lr) * 32 + lk];
#pragma unroll
        for (int mi = 0; mi < 4; ++mi)
#pragma unroll
            for (int ni = 0; ni < 4; ++ni)
                acc[mi][ni] = __builtin_amdgcn_mfma_f32_16x16x32_bf16(af[mi], bv[ni], acc[mi][ni], 0, 0, 0);
        __syncthreads();
    }

    const int row0 = brow + wr * 64 + ((lane >> 4) << 2);
    const int col0 = bcol + wc * 64 + lr;
#pragma unroll
    for (int mi = 0; mi < 4; ++mi) {
#pragma unroll
        for (int ni = 0; ni < 4; ++ni) {
            const int col = col0 + ni * 16;
            const float bvv = bias[col];
#pragma unroll
            for (int r = 0; r < 4; ++r) {
                const int row = row0 + mi * 16 + r;
                outf[(size_t)row * HD + col] = acc[mi][ni][r] + bvv;
            }
        }
    }
}

// ---------------------------------------------------------------------------
// Fused causal retention + PV, closed-form decay mask.
// Grid: (8 qb-pairs, 2 kv-parities, 16 heads) = 256 blocks x 512 threads.
// ---------------------------------------------------------------------------
__global__ __launch_bounds__(512) void retention_fused_k(
    const bf16* __restrict__ qr, const bf16* __restrict__ kr,
    const bf16* __restrict__ vT,
    float* __restrict__ po0, float* __restrict__ po1,
    float* __restrict__ pr0, float* __restrict__ pr1)
{
    __shared__ unsigned short P_lds[128 * 128];  // 32 KB, XOR-swizzled cols
    __shared__ float rsum_lds[4][128];

    const int tid = threadIdx.x;
    const int lane = tid & 63;
    const int wid = tid >> 6;          // 0..7
    const int wr64 = (wid >> 2) * 64;  // q-row half
    const int wc = wid & 3;            // t-quarter (QK) / d-quarter (PV)
    const int lr = lane & 15;
    const int g = lane >> 4;           // 0..3
    const int lk = g << 3;
    const int pidx = blockIdx.x;       // 0..7
    const int parity = blockIdx.y;     // 0..1
    const int h = blockIdx.z;          // 0..15

    const float decay = logf(1.f - exp2f(-5.f - (float)h));
    float* __restrict__ po = parity ? po1 : po0;
    float* __restrict__ pr = parity ? pr1 : pr0;

    const int swzA = (lr & 7) << 3;    // XOR for P A-frag reads

    for (int sec = 0; sec < 2; ++sec) {
        const int qb = sec ? (15 - pidx) : pidx;
        const int qrow0 = qb * 128;

        // Q fragments for this wave's 64 rows (K = 128 = 4 ksteps), resident
        bf16x8 af[4][4];
#pragma unroll
        for (int mi = 0; mi < 4; ++mi)
#pragma unroll
            for (int ks = 0; ks < 4; ++ks)
                af[mi][ks] = *(const bf16x8*)&qr[(size_t)(qrow0 + wr64 + mi * 16 + lr) * HD +
                                                 h * KD + ks * 32 + lk];

        f32x4 acc_o[4][4] = {};
        float rs[4][4] = {};

        for (int tb = parity; tb <= qb; tb += 2) {
            const int t0 = tb * 128;

            // ---- QK^T: per-wave 64q x 32t ----
            f32x4 acc_p[4][2] = {};
#pragma unroll
            for (int ks = 0; ks < 4; ++ks) {
                const bf16x8 b0 = *(const bf16x8*)&kr[(size_t)(t0 + wc * 32 + lr) * HD +
                                                      h * KD + ks * 32 + lk];
                const bf16x8 b1 = *(const bf16x8*)&kr[(size_t)(t0 + wc * 32 + 16 + lr) * HD +
                                                      h * KD + ks * 32 + lk];
#pragma unroll
                for (int mi = 0; mi < 4; ++mi) {
                    acc_p[mi][0] = __builtin_amdgcn_mfma_f32_16x16x32_bf16(af[mi][ks], b0, acc_p[mi][0], 0, 0, 0);
                    acc_p[mi][1] = __builtin_amdgcn_mfma_f32_16x16x32_bf16(af[mi][ks], b1, acc_p[mi][1], 0, 0, 0);
                }
            }

            // ---- mask (closed form) + P -> LDS (bf16) + raw row sums ----
#pragma unroll
            for (int mi = 0; mi < 4; ++mi) {
#pragma unroll
                for (int r = 0; r < 4; ++r) {
                    const int rl = g * 4 + r;
                    const int row_l = wr64 + mi * 16 + rl;
                    const int s_g = qrow0 + row_l;
                    const int t_g0 = t0 + wc * 32 + lr;
                    const int t_g1 = t_g0 + 16;
                    const float e0 = (t_g0 <= s_g) ? __expf(decay * (float)(s_g - t_g0)) : 0.f;
                    const float e1 = (t_g1 <= s_g) ? __expf(decay * (float)(s_g - t_g1)) : 0.f;
                    const float p0 = acc_p[mi][0][r] * e0;
                    const float p1 = acc_p[mi][1][r] * e1;
                    const int sw = (rl & 7) << 3;
                    P_lds[row_l * 128 + ((wc * 32 + lr) ^ sw)] = f2bfu(p0);
                    P_lds[row_l * 128 + ((wc * 32 + 16 + lr) ^ sw)] = f2bfu(p1);
                    rs[mi][r] += p0 + p1;
                }
            }
            __syncthreads();

            // ---- PV: per-wave 64q x 64d, K=128 over this kv tile ----
#pragma unroll
            for (int ks2 = 0; ks2 < 4; ++ks2) {
                bf16x8 a2[4], b2[4];
#pragma unroll
                for (int mi = 0; mi < 4; ++mi)
                    a2[mi] = *(const bf16x8*)&P_lds[(wr64 + mi * 16 + lr) * 128 +
                                                    ((ks2 * 32 + lk) ^ swzA)];
#pragma unroll
                for (int ni = 0; ni < 4; ++ni)
                    b2[ni] = *(const bf16x8*)&vT[(size_t)(h * DH + wc * 64 + ni * 16 + lr) * TT +
                                                 t0 + ks2 * 32 + lk];
#pragma unroll
                for (int mi = 0; mi < 4; ++mi)
#pragma unroll
                    for (int ni = 0; ni < 4; ++ni)
                        acc_o[mi][ni] = __builtin_amdgcn_mfma_f32_16x16x32_bf16(a2[mi], b2[ni], acc_o[mi][ni], 0, 0, 0);
            }
            __syncthreads();
        }

        // ---- raw rowsum: reduce over 16 lanes, combine 4 wc-waves via LDS ----
#pragma unroll
        for (int mi = 0; mi < 4; ++mi)
#pragma unroll
            for (int r = 0; r < 4; ++r) {
                float v = rs[mi][r];
                v += __shfl_xor(v, 1);
                v += __shfl_xor(v, 2);
                v += __shfl_xor(v, 4);
                v += __shfl_xor(v, 8);
                if (lr == 0) rsum_lds[wc][wr64 + mi * 16 + g * 4 + r] = v;
            }
        __syncthreads();
        if (tid < 128)
            pr[(size_t)h * TT + qrow0 + tid] =
                rsum_lds[0][tid] + rsum_lds[1][tid] + rsum_lds[2][tid] + rsum_lds[3][tid];

        // ---- raw out partial [128 q][256 d] ----
#pragma unroll
        for (int mi = 0; mi < 4; ++mi)
#pragma unroll
            for (int ni = 0; ni < 4; ++ni)
#pragma unroll
                for (int r = 0; r < 4; ++r) {
                    const int row_l = wr64 + mi * 16 + g * 4 + r;
                    const int col = wc * 64 + ni * 16 + lr;
                    po[(size_t)(qrow0 + row_l) * VD + h * DH + col] = acc_o[mi][ni][r];
                }
        __syncthreads();
    }
}

// ---------------------------------------------------------------------------
// Combine parity partials -> scale by norm/denom -> LN(256) -> silu-gate (bf16)
// ---------------------------------------------------------------------------
__global__ __launch_bounds__(256) void ln_gate_k(const float* __restrict__ po0,
                                                 const float* __restrict__ po1,
                                                 const float* __restrict__ pr0,
                                                 const float* __restrict__ pr1,
                                                 const bf16* __restrict__ sg,
                                                 bf16* __restrict__ gated) {
    const int tid = threadIdx.x;
    const int lane = tid & 63;
    const size_t ridx = (size_t)blockIdx.x * 4 + (tid >> 6);  // = s*16 + h
    const int h = (int)(ridx & 15);
    const int s = (int)(ridx >> 4);

    const float decay = logf(1.f - exp2f(-5.f - (float)h));
    const float Sm = -expm1f(decay * (float)(s + 1)) * exp2f(5.f + (float)h);
    const float norm = rsqrtf(Sm);
    const float raw = pr0[(size_t)h * TT + s] + pr1[(size_t)h * TT + s];
    const float scale = norm / fmaxf(1.f, fabsf(raw * norm));

    float4 a = *(const float4*)(po0 + ridx * 256 + lane * 4);
    float4 b = *(const float4*)(po1 + ridx * 256 + lane * 4);
    float vv[4] = {(a.x + b.x) * scale, (a.y + b.y) * scale,
                   (a.z + b.z) * scale, (a.w + b.w) * scale};
    float sm = vv[0] + vv[1] + vv[2] + vv[3];
    float sq = vv[0] * vv[0] + vv[1] * vv[1] + vv[2] * vv[2] + vv[3] * vv[3];
#pragma unroll
    for (int o = 1; o < 64; o <<= 1) {
        sm += __shfl_xor(sm, o);
        sq += __shfl_xor(sq, o);
    }
    const float mu = sm * (1.f / 256.f);
    const float var = sq * (1.f / 256.f) - mu * mu;
    const float rstd = rsqrtf(var + 1e-6f);
    const bf16* sgp = sg + ridx * 256 + lane * 4;
    bf16* gp = gated + ridx * 256 + lane * 4;
    bf16 ob[4];
#pragma unroll
    for (int i = 0; i < 4; ++i)
        ob[i] = f2bf((vv[i] - mu) * rstd * __bfloat162float(sgp[i]));
    *(uint2*)gp = *(const uint2*)ob;
}

// ---------------------------------------------------------------------------
extern "C" void kernel_launch(void* const* d_in, const int* in_sizes, int n_in,
                              void* d_out, int out_size, void* d_ws, size_t ws_size,
                              hipStream_t stream) {
    const float* hidden = (const float*)d_in[0];
    const float* Wq = (const float*)d_in[1];
    const float* bq = (const float*)d_in[2];
    const float* Wk = (const float*)d_in[3];
    const float* bk = (const float*)d_in[4];
    const float* Wv = (const float*)d_in[5];
    const float* bvp = (const float*)d_in[6];
    const float* Wg = (const float*)d_in[7];
    const float* bg = (const float*)d_in[8];
    const float* Wo = (const float*)d_in[9];
    const float* bo = (const float*)d_in[10];
    const float* sinT = (const float*)d_in[11];
    const float* cosT = (const float*)d_in[12];
    // d_in[13] = decay_mask: unused (closed-form in-kernel)
    float* out = (float*)d_out;

    char* p = (char*)d_ws;
    bf16* hb = (bf16*)p;    p += (size_t)TT * HD * 2;
    bf16* Wcat = (bf16*)p;  p += (size_t)(HD + HD + VD + VD) * HD * 2;  // 12288 x 2048
    bf16* WoT = (bf16*)p;   p += (size_t)HD * VD * 2;
    bf16* qr = (bf16*)p;    p += (size_t)TT * HD * 2;
    bf16* kr = (bf16*)p;    p += (size_t)TT * HD * 2;
    bf16* vtmp = (bf16*)p;  p += (size_t)TT * VD * 2;
    bf16* vT = (bf16*)p;    p += (size_t)VD * TT * 2;
    bf16* sg = (bf16*)p;    p += (size_t)TT * VD * 2;
    float* po0 = (float*)p; p += (size_t)TT * VD * 4;
    float* po1 = (float*)p; p += (size_t)TT * VD * 4;
    float* pr0 = (float*)p; p += (size_t)NH * TT * 4;
    float* pr1 = (float*)p; p += (size_t)NH * TT * 4;
    bf16* gated = (bf16*)p; p += (size_t)TT * VD * 2;

    // 1) dtype conversions / weight transposes (into concatenated Wcat)
    f32_to_bf16_k<<<TT * HD / 1024, 256, 0, stream>>>(hidden, hb, TT * HD);
    transpose_tb_k<<<dim3(HD / 32, HD / 32), 256, 0, stream>>>(Wq, Wcat, HD, HD);
    transpose_tb_k<<<dim3(HD / 32, HD / 32), 256, 0, stream>>>(Wk, Wcat + (size_t)2048 * HD, HD, HD);
    transpose_tb_k<<<dim3(VD / 32, HD / 32), 256, 0, stream>>>(Wv, Wcat + (size_t)4096 * HD, HD, VD);
    transpose_tb_k<<<dim3(VD / 32, HD / 32), 256, 0, stream>>>(Wg, Wcat + (size_t)8192 * HD, HD, VD);
    transpose_tb_k<<<dim3(HD / 32, VD / 32), 256, 0, stream>>>(Wo, WoT, VD, HD);

    // 2) fused QKVG projection (8-phase 256^2), then V transpose
    gemm_qkvg_k<<<384, 512, 0, stream>>>(hb, Wcat, bq, bk, bvp, bg, sinT, cosT,
                                         qr, kr, vtmp, sg);
    transpose_bf16_k<<<dim3(VD / 64, TT / 64), 256, 0, stream>>>(vtmp, vT);

    // 3) fused causal retention + PV (raw partials per kv-parity)
    retention_fused_k<<<dim3(8, 2, NH), 512, 0, stream>>>(qr, kr, vT, po0, po1, pr0, pr1);

    // 4) combine + groupnorm + gate, then output projection
    ln_gate_k<<<TT * NH / 4, 256, 0, stream>>>(po0, po1, pr0, pr1, sg, gated);
    gemm_out_k<<<256, 256, 0, stream>>>(gated, WoT, bo, out);
}

// Round 6
// 420.529 us; speedup vs baseline: 1.1803x; 1.1803x over previous
//
#include <hip/hip_runtime.h>
#include <hip/hip_bf16.h>

typedef __hip_bfloat16 bf16;
typedef __attribute__((ext_vector_type(8))) __bf16 bf16x8;
typedef __attribute__((ext_vector_type(4))) float f32x4;

constexpr int TT = 2048;   // sequence length
constexpr int HD = 2048;   // hidden dim
constexpr int VD = 4096;   // value dim
constexpr int KD = 128;    // key dim per head
constexpr int NH = 16;     // heads
constexpr int DH = 256;    // head dim of v
constexpr float K_SCALING = 0.08838834764831845f;  // 128^-0.5

__device__ __forceinline__ bf16 f2bf(float x) { return __float2bfloat16(x); }
__device__ __forceinline__ unsigned short f2bfu(float x) {
    bf16 b = __float2bfloat16(x);
    return *reinterpret_cast<unsigned short*>(&b);
}

// ---------------------------------------------------------------------------
// f32 -> bf16 linear convert (4 elems/thread)
// ---------------------------------------------------------------------------
__global__ __launch_bounds__(256) void f32_to_bf16_k(const float* __restrict__ in,
                                                     bf16* __restrict__ outb, int n) {
    int i = (blockIdx.x * 256 + threadIdx.x) * 4;
    if (i >= n) return;
    float4 v = *(const float4*)(in + i);
    bf16 tmp[4] = {f2bf(v.x), f2bf(v.y), f2bf(v.z), f2bf(v.w)};
    *(uint2*)(outb + i) = *(const uint2*)tmp;  // 8B store
}

// ---------------------------------------------------------------------------
// W[R][C] f32 -> WT[C][R] bf16  (32x32 LDS tile transpose)
// ---------------------------------------------------------------------------
__global__ __launch_bounds__(256) void transpose_tb_k(const float* __restrict__ W,
                                                      bf16* __restrict__ WT, int R, int C) {
    __shared__ float tile[32][33];
    const int tx = threadIdx.x & 31, ty = threadIdx.x >> 5;  // 32 x 8
    const int x = blockIdx.x * 32 + tx;
    const int y0 = blockIdx.y * 32;
#pragma unroll
    for (int j = 0; j < 4; ++j)
        tile[ty + j * 8][tx] = W[(size_t)(y0 + ty + j * 8) * C + x];
    __syncthreads();
    const int xt = y0 + tx;          // WT col (= W row)
    const int yt0 = blockIdx.x * 32; // WT row block (= W col)
#pragma unroll
    for (int j = 0; j < 4; ++j)
        WT[(size_t)(yt0 + ty + j * 8) * R + xt] = f2bf(tile[tx][ty + j * 8]);
}

// ---------------------------------------------------------------------------
// bf16 transpose: in[T][VD] -> out[VD][T], 64x64 LDS tiles, b128 in/out
// ---------------------------------------------------------------------------
__global__ __launch_bounds__(256) void transpose_bf16_k(const bf16* __restrict__ in,
                                                        bf16* __restrict__ outb) {
    __shared__ unsigned short sT[64 * 72];  // stride 72 halves (144B, b128-aligned)
    const int tid = threadIdx.x;
    const int x0 = blockIdx.x * 64;  // d
    const int y0 = blockIdx.y * 64;  // t
    {
        const int lt = tid >> 2;           // 0..63 (t local)
        const int c0 = (tid & 3) << 4;     // 0,16,32,48 (d local)
        unsigned short e[16];
        *(bf16x8*)&e[0] = *(const bf16x8*)&in[(size_t)(y0 + lt) * VD + x0 + c0];
        *(bf16x8*)&e[8] = *(const bf16x8*)&in[(size_t)(y0 + lt) * VD + x0 + c0 + 8];
#pragma unroll
        for (int i = 0; i < 16; ++i) {
            const int c = c0 + i;
            sT[c * 72 + (lt ^ (((c >> 3) & 7) << 3))] = e[i];
        }
    }
    __syncthreads();
    {
        const int c = tid >> 2;            // 0..63 (d local)
        const int r0 = (tid & 3) << 4;     // 0,16,32,48 (t local)
        const int xs = ((c >> 3) & 7) << 3;
#pragma unroll
        for (int s2 = 0; s2 < 16; s2 += 8) {
            bf16x8 v = *(const bf16x8*)&sT[c * 72 + ((r0 + s2) ^ xs)];
            *(bf16x8*)&outb[(size_t)(x0 + c) * TT + y0 + r0 + s2] = v;
        }
    }
}

// ---------------------------------------------------------------------------
// Fused QKVG GEMM, 8-phase 256x256 schedule (BK=64, 2 K-tiles/iter).
// C[2048,12288] = hb[2048,2048] @ Wcat[12288,2048]^T
// Segments: [0,2048)=Q(rope) [2048,4096)=K(rope*scale) [4096,8192)=V [8192,12288)=G(silu)
// Counted vmcnt(6) at END of ph3/ph7 (before closing barrier) so every wave's
// wait is barrier-separated from every other wave's reads of the awaited tile.
// ---------------------------------------------------------------------------
#define GLL(gptr, lptr) __builtin_amdgcn_global_load_lds( \
    (const __attribute__((address_space(1))) void*)(gptr), \
    (__attribute__((address_space(3))) void*)(lptr), 16, 0, 0)

#define STAGE_A(nb, qm, k1) \
    GLL(gA0 + (size_t)((qm) * 64) * HD + (k1), sA + (nb) + (qm) * 4096 + w * 512); \
    GLL(gA0 + (size_t)((qm) * 64 + 128) * HD + (k1), sA + (nb) + (qm) * 4096 + 8192 + w * 512)

#define STAGE_B(nb, qn, k1) \
    GLL(gB0 + (size_t)((qn) * 32) * HD + (k1), sB + (nb) + (qn) * 2048 + (w & 3) * 512 + (w >> 2) * 4096); \
    GLL(gB0 + (size_t)((qn) * 32 + 128) * HD + (k1), sB + (nb) + (qn) * 2048 + 8192 + (w & 3) * 512 + (w >> 2) * 4096)

#define WAIT6 asm volatile("s_waitcnt vmcnt(6)" ::: "memory")
#define WAIT0V asm volatile("s_waitcnt vmcnt(0)" ::: "memory")
#define MEMF asm volatile("" ::: "memory")
#define BAR __builtin_amdgcn_s_barrier()

#define LDA(dst, cb, qm) \
    _Pragma("unroll") for (int mi = 0; mi < 4; ++mi) { \
        const int r_ = wr * 128 + (qm) * 64 + mi * 16 + lr; \
        _Pragma("unroll") for (int ks = 0; ks < 2; ++ks) \
            dst[mi][ks] = *(const bf16x8*)&sA[(cb) + r_ * 64 + (((ks * 4 + g) ^ (lr & 7)) << 3)]; \
    }

#define LDB(dst, cb, qn) \
    _Pragma("unroll") for (int ni = 0; ni < 2; ++ni) { \
        const int n_ = wcn * 64 + (qn) * 32 + ni * 16 + lr; \
        _Pragma("unroll") for (int ks = 0; ks < 2; ++ks) \
            dst[ni][ks] = *(const bf16x8*)&sB[(cb) + n_ * 64 + (((ks * 4 + g) ^ (lr & 7)) << 3)]; \
    }

#define MFMAQ(qm, qn, RA, RB) \
    __builtin_amdgcn_s_setprio(1); \
    _Pragma("unroll") for (int mi = 0; mi < 4; ++mi) \
        _Pragma("unroll") for (int ni = 0; ni < 2; ++ni) \
            _Pragma("unroll") for (int ks = 0; ks < 2; ++ks) \
                acc[(qm) * 4 + mi][(qn) * 2 + ni] = __builtin_amdgcn_mfma_f32_16x16x32_bf16( \
                    RA[mi][ks], RB[ni][ks], acc[(qm) * 4 + mi][(qn) * 2 + ni], 0, 0, 0); \
    __builtin_amdgcn_s_setprio(0);

__global__ __launch_bounds__(512, 2) void gemm_qkvg_k(
    const bf16* __restrict__ Ag, const bf16* __restrict__ Bg,
    const float* __restrict__ bq, const float* __restrict__ bk,
    const float* __restrict__ bvp, const float* __restrict__ bg,
    const float* __restrict__ sinT, const float* __restrict__ cosT,
    bf16* __restrict__ qr, bf16* __restrict__ kr,
    bf16* __restrict__ vtmp, bf16* __restrict__ sg)
{
    __shared__ unsigned short sA[2 * 256 * 64];  // 64 KB: buf0 @0, buf1 @16384
    __shared__ unsigned short sB[2 * 256 * 64];  // 64 KB

    const int tid = threadIdx.x;
    const int lane = tid & 63;
    const int w = tid >> 6;        // 0..7
    const int wr = w >> 2;         // 0..1  M half
    const int wcn = w & 3;         // 0..3  N quarter
    const int lr = lane & 15;
    const int g = lane >> 4;

    // XCD-aware swizzle: 384 blocks, 48/XCD
    const int flat = blockIdx.x;
    const int swz = (flat & 7) * 48 + (flat >> 3);
    const int brow = (swz & 7) * 256;
    const int by = swz >> 3;          // 0..47
    const int bcol = by * 256;

    // staging per-lane source (inverse-swizzled col-block; LDS dest linear)
    const int srow = lane >> 3;             // row within 8-row wave chunk
    const int sblk = (lane & 7) ^ srow;     // swizzled 16B col-block
    const bf16* gA0 = Ag + (size_t)(brow + w * 8 + srow) * HD + sblk * 8;
    const bf16* gB0 = Bg + (size_t)(bcol + (w & 3) * 8 + (w >> 2) * 64 + srow) * HD + sblk * 8;

    f32x4 acc[8][4] = {};
    bf16x8 ra0[4][2], ra1[4][2], rb[2][2];

    // prologue: 7 half-tiles in consumption order; then wait+barrier so ALL
    // waves' t0 slices are resident before any wave reads them.
    STAGE_A(0, 0, 0);        // t0.Ah0
    STAGE_B(0, 0, 0);        // t0.Bh0
    STAGE_A(0, 1, 0);        // t0.Ah1
    STAGE_B(0, 1, 0);        // t0.Bh1
    STAGE_A(16384, 0, 64);   // t1.Ah0
    STAGE_B(16384, 0, 64);   // t1.Bh0
    STAGE_A(16384, 1, 64);   // t1.Ah1
    WAIT6; MEMF; BAR;        // t0 fully landed for every wave

    // steady loop: iter I computes tiles (2I, 2I+1), stages (2I+1).Bh1 + t(2I+2) + t(2I+3).{Ah0,Bh0,Ah1}
    for (int I = 0; I < 15; ++I) {
        const int kA = I * 128;
        // ph0: tile 2I quad(0,0)
        LDA(ra0, 0, 0) LDB(rb, 0, 0)
        STAGE_B(16384, 1, kA + 64);        // (2I+1).Bh1
        MEMF; BAR;
        MFMAQ(0, 0, ra0, rb)
        BAR;
        // ph1: quad(1,0)
        LDA(ra1, 0, 1)
        STAGE_A(0, 0, kA + 128);           // (2I+2).Ah0
        MEMF; BAR;
        MFMAQ(1, 0, ra1, rb)
        BAR;
        // ph2: quad(1,1)
        LDB(rb, 0, 1)
        STAGE_B(0, 0, kA + 128);           // (2I+2).Bh0
        MEMF; BAR;
        MFMAQ(1, 1, ra1, rb)
        BAR;
        // ph3: quad(0,1) (no reads: ra0/rb live) — wait covers t(2I+1) for ph4-6
        STAGE_A(0, 1, kA + 128);           // (2I+2).Ah1
        WAIT6; MEMF; BAR;
        MFMAQ(0, 1, ra0, rb)
        BAR;
        // ph4: tile 2I+1 quad(0,0)
        LDA(ra0, 16384, 0) LDB(rb, 16384, 0)
        STAGE_B(0, 1, kA + 128);           // (2I+2).Bh1
        MEMF; BAR;
        MFMAQ(0, 0, ra0, rb)
        BAR;
        // ph5: quad(1,0)
        LDA(ra1, 16384, 1)
        STAGE_A(16384, 0, kA + 192);       // (2I+3).Ah0
        MEMF; BAR;
        MFMAQ(1, 0, ra1, rb)
        BAR;
        // ph6: quad(1,1)
        LDB(rb, 16384, 1)
        STAGE_B(16384, 0, kA + 192);       // (2I+3).Bh0
        MEMF; BAR;
        MFMAQ(1, 1, ra1, rb)
        BAR;
        // ph7: quad(0,1) — wait covers t(2I+2) for next iter ph0-2
        STAGE_A(16384, 1, kA + 192);       // (2I+3).Ah1
        WAIT6; MEMF; BAR;
        MFMAQ(0, 1, ra0, rb)
        BAR;
    }
    // last iter (tiles 30, 31): stage only t31.Bh1; full drain at ph3.
    {
        LDA(ra0, 0, 0) LDB(rb, 0, 0)
        STAGE_B(16384, 1, 1984);           // t31.Bh1
        MEMF; BAR;
        MFMAQ(0, 0, ra0, rb)
        BAR;
        LDA(ra1, 0, 1)
        MEMF; BAR;
        MFMAQ(1, 0, ra1, rb)
        BAR;
        LDB(rb, 0, 1)
        MEMF; BAR;
        MFMAQ(1, 1, ra1, rb)
        BAR;
        WAIT0V; MEMF; BAR;                 // t31 fully landed for every wave
        MFMAQ(0, 1, ra0, rb)
        // tile 31: no staging left, no barriers needed
        LDA(ra0, 16384, 0) LDB(rb, 16384, 0)
        MFMAQ(0, 0, ra0, rb)
        LDA(ra1, 16384, 1)
        MFMAQ(1, 0, ra1, rb)
        LDB(rb, 16384, 1)
        MFMAQ(1, 1, ra1, rb)
        MFMAQ(0, 1, ra0, rb)
    }

    // ---- epilogue ----
#pragma unroll
    for (int M = 0; M < 8; ++M) {
        const int row = brow + wr * 128 + (M >> 2) * 64 + (M & 3) * 16 + g * 4;
#pragma unroll
        for (int N = 0; N < 4; ++N) {
            const int ncol = bcol + wcn * 64 + (N >> 1) * 32 + (N & 1) * 16 + lr;
            if (by < 16) {
                // Q or K with fused RoPE
                const bool isK = (by >= 8);
                const int col = ncol - (isK ? 2048 : 0);
                const float bvv = (isK ? bk : bq)[col];
                const float scale = isK ? K_SCALING : 1.f;
                bf16* outb = isK ? kr : qr;
                const int d = col & (KD - 1);
#pragma unroll
                for (int r = 0; r < 4; ++r) {
                    float v = (acc[M][N][r] + bvv) * scale;
                    float o = __shfl_xor(v, 1);
                    float rot = (col & 1) ? o : -o;
                    outb[(size_t)(row + r) * HD + col] =
                        f2bf(v * cosT[(row + r) * KD + d] + rot * sinT[(row + r) * KD + d]);
                }
            } else if (by < 32) {
                const int col = ncol - 4096;
                const float bvv = bvp[col];
#pragma unroll
                for (int r = 0; r < 4; ++r)
                    vtmp[(size_t)(row + r) * VD + col] = f2bf(acc[M][N][r] + bvv);
            } else {
                const int col = ncol - 8192;
                const float bvv = bg[col];
#pragma unroll
                for (int r = 0; r < 4; ++r) {
                    float v = acc[M][N][r] + bvv;
                    sg[(size_t)(row + r) * VD + col] = f2bf(v / (1.f + __expf(-v)));
                }
            }
        }
    }
}

// ---------------------------------------------------------------------------
// Output GEMM: out[2048,2048] = gated[2048,4096] @ WoT[2048,4096]^T + bo
// 128x128 tile, 4 waves, BK=32 (m97 structure; 256 blocks)
// ---------------------------------------------------------------------------
__global__ __launch_bounds__(256) void gemm_out_k(
    const bf16* __restrict__ Ag, const bf16* __restrict__ Bg,
    const float* __restrict__ bias, float* __restrict__ outf)
{
    __shared__ unsigned short sOA[128 * 32];
    __shared__ unsigned short sOB[128 * 32];

    const int flat = blockIdx.x;
    const int swz = (flat & 7) * 32 + (flat >> 3);
    const int brow = (swz & 15) * 128;
    const int bcol = (swz >> 4) * 128;

    const int tid = threadIdx.x;
    const int lane = tid & 63;
    const int wid = tid >> 6;
    const int wr = wid >> 1, wc = wid & 1;

    f32x4 acc[4][4] = {};

    const int lr = lane & 15;
    const int lk = (lane >> 4) << 3;
    const int r0 = tid >> 2;
    const int c0 = (tid & 3) << 3;
    const int ldsw = (tid & 192) << 3;

    for (int k0 = 0; k0 < VD; k0 += 32) {
        const bf16* gA = Ag + (size_t)(brow + r0) * VD + k0 + c0;
        const bf16* gB = Bg + (size_t)(bcol + r0) * VD + k0 + c0;
        GLL(gA, sOA + ldsw);
        GLL(gB, sOB + ldsw);
        GLL(gA + 64 * VD, sOA + 2048 + ldsw);
        GLL(gB + 64 * VD, sOB + 2048 + ldsw);
        __syncthreads();

        bf16x8 af[4], bv[4];
#pragma unroll
        for (int mi = 0; mi < 4; ++mi)
            af[mi] = *(const bf16x8*)&sOA[(wr * 64 + mi * 16 + lr) * 32 + lk];
#pragma unroll
        for (int ni = 0; ni < 4; ++ni)
            bv[ni] = *(const bf16x8*)&sOB[(wc * 64 + ni * 16 + lr) * 32 + lk];
#pragma unroll
        for (int mi = 0; mi < 4; ++mi)
#pragma unroll
            for (int ni = 0; ni < 4; ++ni)
                acc[mi][ni] = __builtin_amdgcn_mfma_f32_16x16x32_bf16(af[mi], bv[ni], acc[mi][ni], 0, 0, 0);
        __syncthreads();
    }

    const int row0 = brow + wr * 64 + ((lane >> 4) << 2);
    const int col0 = bcol + wc * 64 + lr;
#pragma unroll
    for (int mi = 0; mi < 4; ++mi) {
#pragma unroll
        for (int ni = 0; ni < 4; ++ni) {
            const int col = col0 + ni * 16;
            const float bvv = bias[col];
#pragma unroll
            for (int r = 0; r < 4; ++r) {
                const int row = row0 + mi * 16 + r;
                outf[(size_t)row * HD + col] = acc[mi][ni][r] + bvv;
            }
        }
    }
}

// ---------------------------------------------------------------------------
// Fused causal retention + PV, closed-form decay mask.
// Grid: (8 qb-pairs, 2 kv-parities, 16 heads) = 256 blocks x 512 threads.
// ---------------------------------------------------------------------------
__global__ __launch_bounds__(512) void retention_fused_k(
    const bf16* __restrict__ qr, const bf16* __restrict__ kr,
    const bf16* __restrict__ vT,
    float* __restrict__ po0, float* __restrict__ po1,
    float* __restrict__ pr0, float* __restrict__ pr1)
{
    __shared__ unsigned short P_lds[128 * 128];  // 32 KB, XOR-swizzled cols
    __shared__ float rsum_lds[4][128];

    const int tid = threadIdx.x;
    const int lane = tid & 63;
    const int wid = tid >> 6;          // 0..7
    const int wr64 = (wid >> 2) * 64;  // q-row half
    const int wc = wid & 3;            // t-quarter (QK) / d-quarter (PV)
    const int lr = lane & 15;
    const int g = lane >> 4;           // 0..3
    const int lk = g << 3;
    const int pidx = blockIdx.x;       // 0..7
    const int parity = blockIdx.y;     // 0..1
    const int h = blockIdx.z;          // 0..15

    const float decay = logf(1.f - exp2f(-5.f - (float)h));
    float* __restrict__ po = parity ? po1 : po0;
    float* __restrict__ pr = parity ? pr1 : pr0;

    const int swzA = (lr & 7) << 3;    // XOR for P A-frag reads

    for (int sec = 0; sec < 2; ++sec) {
        const int qb = sec ? (15 - pidx) : pidx;
        const int qrow0 = qb * 128;

        // Q fragments for this wave's 64 rows (K = 128 = 4 ksteps), resident
        bf16x8 af[4][4];
#pragma unroll
        for (int mi = 0; mi < 4; ++mi)
#pragma unroll
            for (int ks = 0; ks < 4; ++ks)
                af[mi][ks] = *(const bf16x8*)&qr[(size_t)(qrow0 + wr64 + mi * 16 + lr) * HD +
                                                 h * KD + ks * 32 + lk];

        f32x4 acc_o[4][4] = {};
        float rs[4][4] = {};

        for (int tb = parity; tb <= qb; tb += 2) {
            const int t0 = tb * 128;

            // ---- QK^T: per-wave 64q x 32t ----
            f32x4 acc_p[4][2] = {};
#pragma unroll
            for (int ks = 0; ks < 4; ++ks) {
                const bf16x8 b0 = *(const bf16x8*)&kr[(size_t)(t0 + wc * 32 + lr) * HD +
                                                      h * KD + ks * 32 + lk];
                const bf16x8 b1 = *(const bf16x8*)&kr[(size_t)(t0 + wc * 32 + 16 + lr) * HD +
                                                      h * KD + ks * 32 + lk];
#pragma unroll
                for (int mi = 0; mi < 4; ++mi) {
                    acc_p[mi][0] = __builtin_amdgcn_mfma_f32_16x16x32_bf16(af[mi][ks], b0, acc_p[mi][0], 0, 0, 0);
                    acc_p[mi][1] = __builtin_amdgcn_mfma_f32_16x16x32_bf16(af[mi][ks], b1, acc_p[mi][1], 0, 0, 0);
                }
            }

            // ---- mask (closed form) + P -> LDS (bf16) + raw row sums ----
#pragma unroll
            for (int mi = 0; mi < 4; ++mi) {
#pragma unroll
                for (int r = 0; r < 4; ++r) {
                    const int rl = g * 4 + r;
                    const int row_l = wr64 + mi * 16 + rl;
                    const int s_g = qrow0 + row_l;
                    const int t_g0 = t0 + wc * 32 + lr;
                    const int t_g1 = t_g0 + 16;
                    const float e0 = (t_g0 <= s_g) ? __expf(decay * (float)(s_g - t_g0)) : 0.f;
                    const float e1 = (t_g1 <= s_g) ? __expf(decay * (float)(s_g - t_g1)) : 0.f;
                    const float p0 = acc_p[mi][0][r] * e0;
                    const float p1 = acc_p[mi][1][r] * e1;
                    const int sw = (rl & 7) << 3;
                    P_lds[row_l * 128 + ((wc * 32 + lr) ^ sw)] = f2bfu(p0);
                    P_lds[row_l * 128 + ((wc * 32 + 16 + lr) ^ sw)] = f2bfu(p1);
                    rs[mi][r] += p0 + p1;
                }
            }
            __syncthreads();

            // ---- PV: per-wave 64q x 64d, K=128 over this kv tile ----
#pragma unroll
            for (int ks2 = 0; ks2 < 4; ++ks2) {
                bf16x8 a2[4], b2[4];
#pragma unroll
                for (int mi = 0; mi < 4; ++mi)
                    a2[mi] = *(const bf16x8*)&P_lds[(wr64 + mi * 16 + lr) * 128 +
                                                    ((ks2 * 32 + lk) ^ swzA)];
#pragma unroll
                for (int ni = 0; ni < 4; ++ni)
                    b2[ni] = *(const bf16x8*)&vT[(size_t)(h * DH + wc * 64 + ni * 16 + lr) * TT +
                                                 t0 + ks2 * 32 + lk];
#pragma unroll
                for (int mi = 0; mi < 4; ++mi)
#pragma unroll
                    for (int ni = 0; ni < 4; ++ni)
                        acc_o[mi][ni] = __builtin_amdgcn_mfma_f32_16x16x32_bf16(a2[mi], b2[ni], acc_o[mi][ni], 0, 0, 0);
            }
            __syncthreads();
        }

        // ---- raw rowsum: reduce over 16 lanes, combine 4 wc-waves via LDS ----
#pragma unroll
        for (int mi = 0; mi < 4; ++mi)
#pragma unroll
            for (int r = 0; r < 4; ++r) {
                float v = rs[mi][r];
                v += __shfl_xor(v, 1);
                v += __shfl_xor(v, 2);
                v += __shfl_xor(v, 4);
                v += __shfl_xor(v, 8);
                if (lr == 0) rsum_lds[wc][wr64 + mi * 16 + g * 4 + r] = v;
            }
        __syncthreads();
        if (tid < 128)
            pr[(size_t)h * TT + qrow0 + tid] =
                rsum_lds[0][tid] + rsum_lds[1][tid] + rsum_lds[2][tid] + rsum_lds[3][tid];

        // ---- raw out partial [128 q][256 d] ----
#pragma unroll
        for (int mi = 0; mi < 4; ++mi)
#pragma unroll
            for (int ni = 0; ni < 4; ++ni)
#pragma unroll
                for (int r = 0; r < 4; ++r) {
                    const int row_l = wr64 + mi * 16 + g * 4 + r;
                    const int col = wc * 64 + ni * 16 + lr;
                    po[(size_t)(qrow0 + row_l) * VD + h * DH + col] = acc_o[mi][ni][r];
                }
        __syncthreads();
    }
}

// ---------------------------------------------------------------------------
// Combine parity partials -> scale by norm/denom -> LN(256) -> silu-gate (bf16)
// ---------------------------------------------------------------------------
__global__ __launch_bounds__(256) void ln_gate_k(const float* __restrict__ po0,
                                                 const float* __restrict__ po1,
                                                 const float* __restrict__ pr0,
                                                 const float* __restrict__ pr1,
                                                 const bf16* __restrict__ sg,
                                                 bf16* __restrict__ gated) {
    const int tid = threadIdx.x;
    const int lane = tid & 63;
    const size_t ridx = (size_t)blockIdx.x * 4 + (tid >> 6);  // = s*16 + h
    const int h = (int)(ridx & 15);
    const int s = (int)(ridx >> 4);

    const float decay = logf(1.f - exp2f(-5.f - (float)h));
    const float Sm = -expm1f(decay * (float)(s + 1)) * exp2f(5.f + (float)h);
    const float norm = rsqrtf(Sm);
    const float raw = pr0[(size_t)h * TT + s] + pr1[(size_t)h * TT + s];
    const float scale = norm / fmaxf(1.f, fabsf(raw * norm));

    float4 a = *(const float4*)(po0 + ridx * 256 + lane * 4);
    float4 b = *(const float4*)(po1 + ridx * 256 + lane * 4);
    float vv[4] = {(a.x + b.x) * scale, (a.y + b.y) * scale,
                   (a.z + b.z) * scale, (a.w + b.w) * scale};
    float sm = vv[0] + vv[1] + vv[2] + vv[3];
    float sq = vv[0] * vv[0] + vv[1] * vv[1] + vv[2] * vv[2] + vv[3] * vv[3];
#pragma unroll
    for (int o = 1; o < 64; o <<= 1) {
        sm += __shfl_xor(sm, o);
        sq += __shfl_xor(sq, o);
    }
    const float mu = sm * (1.f / 256.f);
    const float var = sq * (1.f / 256.f) - mu * mu;
    const float rstd = rsqrtf(var + 1e-6f);
    const bf16* sgp = sg + ridx * 256 + lane * 4;
    bf16* gp = gated + ridx * 256 + lane * 4;
    bf16 ob[4];
#pragma unroll
    for (int i = 0; i < 4; ++i)
        ob[i] = f2bf((vv[i] - mu) * rstd * __bfloat162float(sgp[i]));
    *(uint2*)gp = *(const uint2*)ob;
}

// ---------------------------------------------------------------------------
extern "C" void kernel_launch(void* const* d_in, const int* in_sizes, int n_in,
                              void* d_out, int out_size, void* d_ws, size_t ws_size,
                              hipStream_t stream) {
    const float* hidden = (const float*)d_in[0];
    const float* Wq = (const float*)d_in[1];
    const float* bq = (const float*)d_in[2];
    const float* Wk = (const float*)d_in[3];
    const float* bk = (const float*)d_in[4];
    const float* Wv = (const float*)d_in[5];
    const float* bvp = (const float*)d_in[6];
    const float* Wg = (const float*)d_in[7];
    const float* bg = (const float*)d_in[8];
    const float* Wo = (const float*)d_in[9];
    const float* bo = (const float*)d_in[10];
    const float* sinT = (const float*)d_in[11];
    const float* cosT = (const float*)d_in[12];
    // d_in[13] = decay_mask: unused (closed-form in-kernel)
    float* out = (float*)d_out;

    char* p = (char*)d_ws;
    bf16* hb = (bf16*)p;    p += (size_t)TT * HD * 2;
    bf16* Wcat = (bf16*)p;  p += (size_t)(HD + HD + VD + VD) * HD * 2;  // 12288 x 2048
    bf16* WoT = (bf16*)p;   p += (size_t)HD * VD * 2;
    bf16* qr = (bf16*)p;    p += (size_t)TT * HD * 2;
    bf16* kr = (bf16*)p;    p += (size_t)TT * HD * 2;
    bf16* vtmp = (bf16*)p;  p += (size_t)TT * VD * 2;
    bf16* vT = (bf16*)p;    p += (size_t)VD * TT * 2;
    bf16* sg = (bf16*)p;    p += (size_t)TT * VD * 2;
    float* po0 = (float*)p; p += (size_t)TT * VD * 4;
    float* po1 = (float*)p; p += (size_t)TT * VD * 4;
    float* pr0 = (float*)p; p += (size_t)NH * TT * 4;
    float* pr1 = (float*)p; p += (size_t)NH * TT * 4;
    bf16* gated = (bf16*)p; p += (size_t)TT * VD * 2;

    // 1) dtype conversions / weight transposes (into concatenated Wcat)
    f32_to_bf16_k<<<TT * HD / 1024, 256, 0, stream>>>(hidden, hb, TT * HD);
    transpose_tb_k<<<dim3(HD / 32, HD / 32), 256, 0, stream>>>(Wq, Wcat, HD, HD);
    transpose_tb_k<<<dim3(HD / 32, HD / 32), 256, 0, stream>>>(Wk, Wcat + (size_t)2048 * HD, HD, HD);
    transpose_tb_k<<<dim3(VD / 32, HD / 32), 256, 0, stream>>>(Wv, Wcat + (size_t)4096 * HD, HD, VD);
    transpose_tb_k<<<dim3(VD / 32, HD / 32), 256, 0, stream>>>(Wg, Wcat + (size_t)8192 * HD, HD, VD);
    transpose_tb_k<<<dim3(HD / 32, VD / 32), 256, 0, stream>>>(Wo, WoT, VD, HD);

    // 2) fused QKVG projection (8-phase 256^2), then V transpose
    gemm_qkvg_k<<<384, 512, 0, stream>>>(hb, Wcat, bq, bk, bvp, bg, sinT, cosT,
                                         qr, kr, vtmp, sg);
    transpose_bf16_k<<<dim3(VD / 64, TT / 64), 256, 0, stream>>>(vtmp, vT);

    // 3) fused causal retention + PV (raw partials per kv-parity)
    retention_fused_k<<<dim3(8, 2, NH), 512, 0, stream>>>(qr, kr, vT, po0, po1, pr0, pr1);

    // 4) combine + groupnorm + gate, then output projection
    ln_gate_k<<<TT * NH / 4, 256, 0, stream>>>(po0, po1, pr0, pr1, sg, gated);
    gemm_out_k<<<256, 256, 0, stream>>>(gated, WoT, bo, out);
}

// Round 7
// 388.319 us; speedup vs baseline: 1.2782x; 1.0829x over previous
//
#include <hip/hip_runtime.h>
#include <hip/hip_bf16.h>

typedef __hip_bfloat16 bf16;
typedef __attribute__((ext_vector_type(8))) __bf16 bf16x8;
typedef __attribute__((ext_vector_type(4))) float f32x4;

constexpr int TT = 2048;   // sequence length
constexpr int HD = 2048;   // hidden dim
constexpr int VD = 4096;   // value dim
constexpr int KD = 128;    // key dim per head
constexpr int NH = 16;     // heads
constexpr int DH = 256;    // head dim of v
constexpr float K_SCALING = 0.08838834764831845f;  // 128^-0.5

__device__ __forceinline__ bf16 f2bf(float x) { return __float2bfloat16(x); }
__device__ __forceinline__ unsigned short f2bfu(float x) {
    bf16 b = __float2bfloat16(x);
    return *reinterpret_cast<unsigned short*>(&b);
}

// ---------------------------------------------------------------------------
// f32 -> bf16 linear convert (4 elems/thread)
// ---------------------------------------------------------------------------
__global__ __launch_bounds__(256) void f32_to_bf16_k(const float* __restrict__ in,
                                                     bf16* __restrict__ outb, int n) {
    int i = (blockIdx.x * 256 + threadIdx.x) * 4;
    if (i >= n) return;
    float4 v = *(const float4*)(in + i);
    bf16 tmp[4] = {f2bf(v.x), f2bf(v.y), f2bf(v.z), f2bf(v.w)};
    *(uint2*)(outb + i) = *(const uint2*)tmp;  // 8B store
}

// ---------------------------------------------------------------------------
// W[R][C] f32 -> WT[C][R] bf16  (64x64 LDS tile, float4 in / bf16x8 out)
// ---------------------------------------------------------------------------
__global__ __launch_bounds__(256) void transpose_tb_k(const float* __restrict__ W,
                                                      bf16* __restrict__ WT, int R, int C) {
    __shared__ unsigned short sT[64 * 72];
    const int t = threadIdx.x;
    const int x0 = blockIdx.x * 64;  // col of W
    const int y0 = blockIdx.y * 64;  // row of W
    {
        const int r = t >> 2;
        const int c0 = (t & 3) << 4;
        const float* src = W + (size_t)(y0 + r) * C + x0 + c0;
        unsigned short e[16];
#pragma unroll
        for (int j = 0; j < 4; ++j) {
            float4 v = *(const float4*)(src + j * 4);
            e[j * 4 + 0] = f2bfu(v.x);
            e[j * 4 + 1] = f2bfu(v.y);
            e[j * 4 + 2] = f2bfu(v.z);
            e[j * 4 + 3] = f2bfu(v.w);
        }
#pragma unroll
        for (int i = 0; i < 16; ++i) {
            const int c = c0 + i;
            sT[c * 72 + (r ^ (((c >> 3) & 7) << 3))] = e[i];
        }
    }
    __syncthreads();
    {
        const int c = t >> 2;
        const int r0 = (t & 3) << 4;
        const int xs = ((c >> 3) & 7) << 3;
#pragma unroll
        for (int s2 = 0; s2 < 16; s2 += 8) {
            bf16x8 v = *(const bf16x8*)&sT[c * 72 + ((r0 + s2) ^ xs)];
            *(bf16x8*)&WT[(size_t)(x0 + c) * R + y0 + r0 + s2] = v;
        }
    }
}

// ---------------------------------------------------------------------------
// bf16 transpose: in[T][VD] -> out[VD][T], 64x64 LDS tiles, b128 in/out
// ---------------------------------------------------------------------------
__global__ __launch_bounds__(256) void transpose_bf16_k(const bf16* __restrict__ in,
                                                        bf16* __restrict__ outb) {
    __shared__ unsigned short sT[64 * 72];
    const int tid = threadIdx.x;
    const int x0 = blockIdx.x * 64;  // d
    const int y0 = blockIdx.y * 64;  // t
    {
        const int lt = tid >> 2;
        const int c0 = (tid & 3) << 4;
        unsigned short e[16];
        *(bf16x8*)&e[0] = *(const bf16x8*)&in[(size_t)(y0 + lt) * VD + x0 + c0];
        *(bf16x8*)&e[8] = *(const bf16x8*)&in[(size_t)(y0 + lt) * VD + x0 + c0 + 8];
#pragma unroll
        for (int i = 0; i < 16; ++i) {
            const int c = c0 + i;
            sT[c * 72 + (lt ^ (((c >> 3) & 7) << 3))] = e[i];
        }
    }
    __syncthreads();
    {
        const int c = tid >> 2;
        const int r0 = (tid & 3) << 4;
        const int xs = ((c >> 3) & 7) << 3;
#pragma unroll
        for (int s2 = 0; s2 < 16; s2 += 8) {
            bf16x8 v = *(const bf16x8*)&sT[c * 72 + ((r0 + s2) ^ xs)];
            *(bf16x8*)&outb[(size_t)(x0 + c) * TT + y0 + r0 + s2] = v;
        }
    }
}

// ---------------------------------------------------------------------------
// Fused QKVG GEMM, 8-phase 256x192 schedule (BK=64, 2 K-tiles/iter).
// C[2048,12288] = hb[2048,2048] @ Wcat[12288,2048]^T
// Grid 8 x 64 = 512 blocks = exactly 2 rounds on 256 CUs (balanced).
// Per-frag epilogue segments: Q[0,2048) K[2048,4096) V[4096,8192) G[8192,12288).
// Counted vmcnt(6) at end of ph3/ph7 (barrier-separated from consumer reads).
// ---------------------------------------------------------------------------
#define GLL(gptr, lptr) __builtin_amdgcn_global_load_lds( \
    (const __attribute__((address_space(1))) void*)(gptr), \
    (__attribute__((address_space(3))) void*)(lptr), 16, 0, 0)

// one GLL = 512 thr x 16B = 64 rows x 128B; unit u covers rows u*64..u*64+63
#define STA(bufs, u, k1) GLL(gA0 + (size_t)((u) * 64) * HD + (k1), sA + (bufs) + (u) * 4096 + tid * 8)
#define STB(bufs, u, k1) GLL(gB0 + (size_t)((u) * 64) * HD + (k1), sB + (bufs) + (u) * 4096 + tid * 8)

#define WAIT6 asm volatile("s_waitcnt vmcnt(6)" ::: "memory")
#define WAIT0V asm volatile("s_waitcnt vmcnt(0)" ::: "memory")
#define MEMF asm volatile("" ::: "memory")
#define BAR __builtin_amdgcn_s_barrier()

#define LDA(dst, cb, qm) \
    _Pragma("unroll") for (int mi = 0; mi < 4; ++mi) { \
        const int r_ = wr * 128 + (qm) * 64 + mi * 16 + lr; \
        _Pragma("unroll") for (int ks = 0; ks < 2; ++ks) \
            dst[mi][ks] = *(const bf16x8*)&sA[(cb) + r_ * 64 + (((ks * 4 + g) ^ (lr & 7)) << 3)]; \
    }

#define LDB01(dst, cb) \
    _Pragma("unroll") for (int ni = 0; ni < 2; ++ni) { \
        const int n_ = wcn * 48 + ni * 16 + lr; \
        _Pragma("unroll") for (int ks = 0; ks < 2; ++ks) \
            dst[ni][ks] = *(const bf16x8*)&sB[(cb) + n_ * 64 + (((ks * 4 + g) ^ (lr & 7)) << 3)]; \
    }

#define LDB2(dst, cb) { \
        const int n_ = wcn * 48 + 32 + lr; \
        _Pragma("unroll") for (int ks = 0; ks < 2; ++ks) \
            dst[ks] = *(const bf16x8*)&sB[(cb) + n_ * 64 + (((ks * 4 + g) ^ (lr & 7)) << 3)]; \
    }

#define Q00 __builtin_amdgcn_s_setprio(1); \
    _Pragma("unroll") for (int mi = 0; mi < 4; ++mi) \
        _Pragma("unroll") for (int ni = 0; ni < 2; ++ni) \
            _Pragma("unroll") for (int ks = 0; ks < 2; ++ks) \
                acc[mi][ni] = __builtin_amdgcn_mfma_f32_16x16x32_bf16(ra0[mi][ks], rb[ni][ks], acc[mi][ni], 0, 0, 0); \
    __builtin_amdgcn_s_setprio(0);
#define Q10 __builtin_amdgcn_s_setprio(1); \
    _Pragma("unroll") for (int mi = 0; mi < 4; ++mi) \
        _Pragma("unroll") for (int ni = 0; ni < 2; ++ni) \
            _Pragma("unroll") for (int ks = 0; ks < 2; ++ks) \
                acc[4 + mi][ni] = __builtin_amdgcn_mfma_f32_16x16x32_bf16(ra1[mi][ks], rb[ni][ks], acc[4 + mi][ni], 0, 0, 0); \
    __builtin_amdgcn_s_setprio(0);
#define Q11 __builtin_amdgcn_s_setprio(1); \
    _Pragma("unroll") for (int mi = 0; mi < 4; ++mi) \
        _Pragma("unroll") for (int ks = 0; ks < 2; ++ks) \
            acc[4 + mi][2] = __builtin_amdgcn_mfma_f32_16x16x32_bf16(ra1[mi][ks], rb2[ks], acc[4 + mi][2], 0, 0, 0); \
    __builtin_amdgcn_s_setprio(0);
#define Q01 __builtin_amdgcn_s_setprio(1); \
    _Pragma("unroll") for (int mi = 0; mi < 4; ++mi) \
        _Pragma("unroll") for (int ks = 0; ks < 2; ++ks) \
            acc[mi][2] = __builtin_amdgcn_mfma_f32_16x16x32_bf16(ra0[mi][ks], rb2[ks], acc[mi][2], 0, 0, 0); \
    __builtin_amdgcn_s_setprio(0);

__global__ __launch_bounds__(512, 2) void gemm_qkvg_k(
    const bf16* __restrict__ Ag, const bf16* __restrict__ Bg,
    const float* __restrict__ bq, const float* __restrict__ bk,
    const float* __restrict__ bvp, const float* __restrict__ bg,
    const float* __restrict__ sinT, const float* __restrict__ cosT,
    bf16* __restrict__ qr, bf16* __restrict__ kr,
    bf16* __restrict__ vtmp, bf16* __restrict__ sg)
{
    __shared__ unsigned short sA[2 * 256 * 64];  // 64 KB: buf0 @0, buf1 @16384
    __shared__ unsigned short sB[2 * 192 * 64];  // 48 KB: buf0 @0, buf1 @12288
    constexpr int BUFA = 16384, BUFB = 12288;

    const int tid = threadIdx.x;
    const int lane = tid & 63;
    const int w = tid >> 6;        // 0..7
    const int wr = w >> 2;         // 0..1  M half (128 rows)
    const int wcn = w & 3;         // 0..3  N quarter (48 cols)
    const int lr = lane & 15;
    const int g = lane >> 4;

    // XCD-aware bijective swizzle: 512 blocks, 64/XCD
    const int flat = blockIdx.x;
    const int swz = (flat & 7) * 64 + (flat >> 3);
    const int brow = (swz & 7) * 256;
    const int bcol = (swz >> 3) * 192;   // 0..63 tiles

    // staging per-lane source (inverse-swizzled col-block; LDS dest linear)
    const bf16* gA0 = Ag + (size_t)(brow + (tid >> 3)) * HD + (((tid & 7) ^ ((tid >> 3) & 7)) << 3);
    const bf16* gB0 = Bg + (size_t)(bcol + (tid >> 3)) * HD + (((tid & 7) ^ ((tid >> 3) & 7)) << 3);

    f32x4 acc[8][3] = {};
    bf16x8 ra0[4][2], ra1[4][2], rb[2][2], rb2[2];

    // prologue: tile0 (A4+B3) + tile1 (A4+B2) = 13 GLL; WAIT6 => tile0 resident
    STA(0, 0, 0); STA(0, 1, 0); STA(0, 2, 0); STA(0, 3, 0);
    STB(0, 0, 0); STB(0, 1, 0); STB(0, 2, 0);
    STA(BUFA, 0, 64); STA(BUFA, 1, 64); STA(BUFA, 2, 64); STA(BUFA, 3, 64);
    STB(BUFB, 0, 64); STB(BUFB, 1, 64);
    WAIT6; MEMF; BAR;

    // steady: iter I computes tiles 2I (buf0), 2I+1 (buf1)
    for (int I = 0; I < 15; ++I) {
        const int kB1 = I * 128 + 64;    // tile 2I+1
        const int kN2 = I * 128 + 128;   // tile 2I+2
        const int kN3 = I * 128 + 192;   // tile 2I+3
        // ph0
        LDA(ra0, 0, 0) LDB01(rb, 0)
        STB(BUFB, 2, kB1);
        MEMF; BAR; Q00 BAR;
        // ph1
        LDA(ra1, 0, 1)
        STA(0, 0, kN2); STA(0, 2, kN2);
        MEMF; BAR; Q10 BAR;
        // ph2
        LDB2(rb2, 0)
        STA(0, 1, kN2); STA(0, 3, kN2);
        MEMF; BAR; Q11 BAR;
        // ph3 (no reads; ra0/rb2 live)
        STB(0, 0, kN2); STB(0, 1, kN2);
        WAIT6; MEMF; BAR; Q01 BAR;
        // ph4
        LDA(ra0, BUFA, 0) LDB01(rb, BUFB)
        STB(0, 2, kN2);
        MEMF; BAR; Q00 BAR;
        // ph5
        LDA(ra1, BUFA, 1)
        STA(BUFA, 0, kN3); STA(BUFA, 2, kN3);
        MEMF; BAR; Q10 BAR;
        // ph6
        LDB2(rb2, BUFB)
        STA(BUFA, 1, kN3); STA(BUFA, 3, kN3);
        MEMF; BAR; Q11 BAR;
        // ph7
        STB(BUFB, 0, kN3); STB(BUFB, 1, kN3);
        WAIT6; MEMF; BAR; Q01 BAR;
    }
    // tail: tiles 30 (buf0), 31 (buf1); stage only B(31)u2; drain at ph3.
    {
        LDA(ra0, 0, 0) LDB01(rb, 0)
        STB(BUFB, 2, 1984);
        MEMF; BAR; Q00 BAR;
        LDA(ra1, 0, 1)
        MEMF; BAR; Q10 BAR;
        LDB2(rb2, 0)
        MEMF; BAR; Q11 BAR;
        WAIT0V; MEMF; BAR; Q01 BAR;
        LDA(ra0, BUFA, 0) LDB01(rb, BUFB)
        Q00
        LDA(ra1, BUFA, 1)
        Q10
        LDB2(rb2, BUFB)
        Q11
        Q01
    }

    // ---- epilogue: per-frag segment dispatch ----
#pragma unroll
    for (int M = 0; M < 8; ++M) {
        const int row = brow + wr * 128 + (M >> 2) * 64 + (M & 3) * 16 + g * 4;
#pragma unroll
        for (int f = 0; f < 3; ++f) {
            const int colg = bcol + wcn * 48 + f * 16 + lr;
            if (colg < 4096) {
                // Q or K with fused RoPE
                const bool isK = (colg >= 2048);
                const int col = colg - (isK ? 2048 : 0);
                const float bvv = (isK ? bk : bq)[col];
                const float scale = isK ? K_SCALING : 1.f;
                bf16* outb = isK ? kr : qr;
                const int d = col & (KD - 1);
#pragma unroll
                for (int r = 0; r < 4; ++r) {
                    float v = (acc[M][f][r] + bvv) * scale;
                    float o = __shfl_xor(v, 1);
                    float rot = (col & 1) ? o : -o;
                    outb[(size_t)(row + r) * HD + col] =
                        f2bf(v * cosT[(row + r) * KD + d] + rot * sinT[(row + r) * KD + d]);
                }
            } else if (colg < 8192) {
                const int col = colg - 4096;
                const float bvv = bvp[col];
#pragma unroll
                for (int r = 0; r < 4; ++r)
                    vtmp[(size_t)(row + r) * VD + col] = f2bf(acc[M][f][r] + bvv);
            } else {
                const int col = colg - 8192;
                const float bvv = bg[col];
#pragma unroll
                for (int r = 0; r < 4; ++r) {
                    float v = acc[M][f][r] + bvv;
                    sg[(size_t)(row + r) * VD + col] = f2bf(v / (1.f + __expf(-v)));
                }
            }
        }
    }
}

// ---------------------------------------------------------------------------
// Output GEMM: out[2048,2048] = gated[2048,4096] @ WoT[2048,4096]^T + bo
// 128x128 tile, 4 waves, BK=32 (m97 structure; 256 blocks)
// ---------------------------------------------------------------------------
__global__ __launch_bounds__(256) void gemm_out_k(
    const bf16* __restrict__ Ag, const bf16* __restrict__ Bg,
    const float* __restrict__ bias, float* __restrict__ outf)
{
    __shared__ unsigned short sOA[128 * 32];
    __shared__ unsigned short sOB[128 * 32];

    const int flat = blockIdx.x;
    const int swz = (flat & 7) * 32 + (flat >> 3);
    const int brow = (swz & 15) * 128;
    const int bcol = (swz >> 4) * 128;

    const int tid = threadIdx.x;
    const int lane = tid & 63;
    const int wid = tid >> 6;
    const int wr = wid >> 1, wc = wid & 1;

    f32x4 acc[4][4] = {};

    const int lr = lane & 15;
    const int lk = (lane >> 4) << 3;
    const int r0 = tid >> 2;
    const int c0 = (tid & 3) << 3;
    const int ldsw = (tid & 192) << 3;

    for (int k0 = 0; k0 < VD; k0 += 32) {
        const bf16* gA = Ag + (size_t)(brow + r0) * VD + k0 + c0;
        const bf16* gB = Bg + (size_t)(bcol + r0) * VD + k0 + c0;
        GLL(gA, sOA + ldsw);
        GLL(gB, sOB + ldsw);
        GLL(gA + 64 * VD, sOA + 2048 + ldsw);
        GLL(gB + 64 * VD, sOB + 2048 + ldsw);
        __syncthreads();

        bf16x8 af[4], bv[4];
#pragma unroll
        for (int mi = 0; mi < 4; ++mi)
            af[mi] = *(const bf16x8*)&sOA[(wr * 64 + mi * 16 + lr) * 32 + lk];
#pragma unroll
        for (int ni = 0; ni < 4; ++ni)
            bv[ni] = *(const bf16x8*)&sOB[(wc * 64 + ni * 16 + lr) * 32 + lk];
#pragma unroll
        for (int mi = 0; mi < 4; ++mi)
#pragma unroll
            for (int ni = 0; ni < 4; ++ni)
                acc[mi][ni] = __builtin_amdgcn_mfma_f32_16x16x32_bf16(af[mi], bv[ni], acc[mi][ni], 0, 0, 0);
        __syncthreads();
    }

    const int row0 = brow + wr * 64 + ((lane >> 4) << 2);
    const int col0 = bcol + wc * 64 + lr;
#pragma unroll
    for (int mi = 0; mi < 4; ++mi) {
#pragma unroll
        for (int ni = 0; ni < 4; ++ni) {
            const int col = col0 + ni * 16;
            const float bvv = bias[col];
#pragma unroll
            for (int r = 0; r < 4; ++r) {
                const int row = row0 + mi * 16 + r;
                outf[(size_t)row * HD + col] = acc[mi][ni][r] + bvv;
            }
        }
    }
}

// ---------------------------------------------------------------------------
// Fused causal retention + PV, closed-form decay mask (factorized a(s)*b(t)).
// Grid: (8 qb-pairs, 2 kv-parities, 16 heads) = 256 blocks x 512 threads.
// ---------------------------------------------------------------------------
__global__ __launch_bounds__(512) void retention_fused_k(
    const bf16* __restrict__ qr, const bf16* __restrict__ kr,
    const bf16* __restrict__ vT,
    float* __restrict__ po0, float* __restrict__ po1,
    float* __restrict__ pr0, float* __restrict__ pr1)
{
    __shared__ unsigned short P_lds[128 * 128];  // 32 KB, XOR-swizzled cols
    __shared__ float rsum_lds[4][128];

    const int tid = threadIdx.x;
    const int lane = tid & 63;
    const int wid = tid >> 6;          // 0..7
    const int wr64 = (wid >> 2) * 64;  // q-row half
    const int wc = wid & 3;            // t-quarter (QK) / d-quarter (PV)
    const int lr = lane & 15;
    const int g = lane >> 4;           // 0..3
    const int lk = g << 3;
    const int pidx = blockIdx.x;       // 0..7
    const int parity = blockIdx.y;     // 0..1
    const int h = blockIdx.z;          // 0..15

    const float decay = logf(1.f - exp2f(-5.f - (float)h));
    float* __restrict__ po = parity ? po1 : po0;
    float* __restrict__ pr = parity ? pr1 : pr0;

    const int swzA = (lr & 7) << 3;    // XOR for P A-frag reads

    // b(t) factors: exp(decay * (t0 - t_g)) = exp(-decay * (wc*32 + lr (+16)))
    const float bfac0 = __expf(decay * (float)(-(wc * 32 + lr)));
    const float bfac1 = __expf(decay * (float)(-(wc * 32 + 16 + lr)));

    for (int sec = 0; sec < 2; ++sec) {
        const int qb = sec ? (15 - pidx) : pidx;
        const int qrow0 = qb * 128;

        // Q fragments for this wave's 64 rows (K = 128 = 4 ksteps), resident
        bf16x8 af[4][4];
#pragma unroll
        for (int mi = 0; mi < 4; ++mi)
#pragma unroll
            for (int ks = 0; ks < 4; ++ks)
                af[mi][ks] = *(const bf16x8*)&qr[(size_t)(qrow0 + wr64 + mi * 16 + lr) * HD +
                                                 h * KD + ks * 32 + lk];

        f32x4 acc_o[4][4] = {};
        float rs[4][4] = {};

        for (int tb = parity; tb <= qb; tb += 2) {
            const int t0 = tb * 128;

            // ---- QK^T: per-wave 64q x 32t ----
            f32x4 acc_p[4][2] = {};
#pragma unroll
            for (int ks = 0; ks < 4; ++ks) {
                const bf16x8 b0 = *(const bf16x8*)&kr[(size_t)(t0 + wc * 32 + lr) * HD +
                                                      h * KD + ks * 32 + lk];
                const bf16x8 b1 = *(const bf16x8*)&kr[(size_t)(t0 + wc * 32 + 16 + lr) * HD +
                                                      h * KD + ks * 32 + lk];
#pragma unroll
                for (int mi = 0; mi < 4; ++mi) {
                    acc_p[mi][0] = __builtin_amdgcn_mfma_f32_16x16x32_bf16(af[mi][ks], b0, acc_p[mi][0], 0, 0, 0);
                    acc_p[mi][1] = __builtin_amdgcn_mfma_f32_16x16x32_bf16(af[mi][ks], b1, acc_p[mi][1], 0, 0, 0);
                }
            }

            // ---- mask a(s)*b(t) + P -> LDS (bf16) + raw row sums ----
#pragma unroll
            for (int mi = 0; mi < 4; ++mi) {
#pragma unroll
                for (int r = 0; r < 4; ++r) {
                    const int rl = g * 4 + r;
                    const int row_l = wr64 + mi * 16 + rl;
                    const int s_g = qrow0 + row_l;
                    const int srel = s_g - t0;                       // >= 0
                    const float a = __expf(decay * (float)srel);
                    const float p0 = (wc * 32 + lr <= srel) ? acc_p[mi][0][r] * a * bfac0 : 0.f;
                    const float p1 = (wc * 32 + 16 + lr <= srel) ? acc_p[mi][1][r] * a * bfac1 : 0.f;
                    const int sw = (rl & 7) << 3;
                    P_lds[row_l * 128 + ((wc * 32 + lr) ^ sw)] = f2bfu(p0);
                    P_lds[row_l * 128 + ((wc * 32 + 16 + lr) ^ sw)] = f2bfu(p1);
                    rs[mi][r] += p0 + p1;
                }
            }
            __syncthreads();

            // ---- PV: per-wave 64q x 64d, K=128 over this kv tile ----
#pragma unroll
            for (int ks2 = 0; ks2 < 4; ++ks2) {
                bf16x8 a2[4], b2[4];
#pragma unroll
                for (int mi = 0; mi < 4; ++mi)
                    a2[mi] = *(const bf16x8*)&P_lds[(wr64 + mi * 16 + lr) * 128 +
                                                    ((ks2 * 32 + lk) ^ swzA)];
#pragma unroll
                for (int ni = 0; ni < 4; ++ni)
                    b2[ni] = *(const bf16x8*)&vT[(size_t)(h * DH + wc * 64 + ni * 16 + lr) * TT +
                                                 t0 + ks2 * 32 + lk];
#pragma unroll
                for (int mi = 0; mi < 4; ++mi)
#pragma unroll
                    for (int ni = 0; ni < 4; ++ni)
                        acc_o[mi][ni] = __builtin_amdgcn_mfma_f32_16x16x32_bf16(a2[mi], b2[ni], acc_o[mi][ni], 0, 0, 0);
            }
            __syncthreads();
        }

        // ---- raw rowsum: reduce over 16 lanes, combine 4 wc-waves via LDS ----
#pragma unroll
        for (int mi = 0; mi < 4; ++mi)
#pragma unroll
            for (int r = 0; r < 4; ++r) {
                float v = rs[mi][r];
                v += __shfl_xor(v, 1);
                v += __shfl_xor(v, 2);
                v += __shfl_xor(v, 4);
                v += __shfl_xor(v, 8);
                if (lr == 0) rsum_lds[wc][wr64 + mi * 16 + g * 4 + r] = v;
            }
        __syncthreads();
        if (tid < 128)
            pr[(size_t)h * TT + qrow0 + tid] =
                rsum_lds[0][tid] + rsum_lds[1][tid] + rsum_lds[2][tid] + rsum_lds[3][tid];

        // ---- raw out partial [128 q][256 d] ----
#pragma unroll
        for (int mi = 0; mi < 4; ++mi)
#pragma unroll
            for (int ni = 0; ni < 4; ++ni)
#pragma unroll
                for (int r = 0; r < 4; ++r) {
                    const int row_l = wr64 + mi * 16 + g * 4 + r;
                    const int col = wc * 64 + ni * 16 + lr;
                    po[(size_t)(qrow0 + row_l) * VD + h * DH + col] = acc_o[mi][ni][r];
                }
        __syncthreads();
    }
}

// ---------------------------------------------------------------------------
// Combine parity partials -> scale by norm/denom -> LN(256) -> silu-gate (bf16)
// ---------------------------------------------------------------------------
__global__ __launch_bounds__(256) void ln_gate_k(const float* __restrict__ po0,
                                                 const float* __restrict__ po1,
                                                 const float* __restrict__ pr0,
                                                 const float* __restrict__ pr1,
                                                 const bf16* __restrict__ sg,
                                                 bf16* __restrict__ gated) {
    const int tid = threadIdx.x;
    const int lane = tid & 63;
    const size_t ridx = (size_t)blockIdx.x * 4 + (tid >> 6);  // = s*16 + h
    const int h = (int)(ridx & 15);
    const int s = (int)(ridx >> 4);

    const float decay = logf(1.f - exp2f(-5.f - (float)h));
    const float Sm = -expm1f(decay * (float)(s + 1)) * exp2f(5.f + (float)h);
    const float norm = rsqrtf(Sm);
    const float raw = pr0[(size_t)h * TT + s] + pr1[(size_t)h * TT + s];
    const float scale = norm / fmaxf(1.f, fabsf(raw * norm));

    float4 a = *(const float4*)(po0 + ridx * 256 + lane * 4);
    float4 b = *(const float4*)(po1 + ridx * 256 + lane * 4);
    float vv[4] = {(a.x + b.x) * scale, (a.y + b.y) * scale,
                   (a.z + b.z) * scale, (a.w + b.w) * scale};
    float sm = vv[0] + vv[1] + vv[2] + vv[3];
    float sq = vv[0] * vv[0] + vv[1] * vv[1] + vv[2] * vv[2] + vv[3] * vv[3];
#pragma unroll
    for (int o = 1; o < 64; o <<= 1) {
        sm += __shfl_xor(sm, o);
        sq += __shfl_xor(sq, o);
    }
    const float mu = sm * (1.f / 256.f);
    const float var = sq * (1.f / 256.f) - mu * mu;
    const float rstd = rsqrtf(var + 1e-6f);
    const bf16* sgp = sg + ridx * 256 + lane * 4;
    bf16* gp = gated + ridx * 256 + lane * 4;
    bf16 ob[4];
#pragma unroll
    for (int i = 0; i < 4; ++i)
        ob[i] = f2bf((vv[i] - mu) * rstd * __bfloat162float(sgp[i]));
    *(uint2*)gp = *(const uint2*)ob;
}

// ---------------------------------------------------------------------------
extern "C" void kernel_launch(void* const* d_in, const int* in_sizes, int n_in,
                              void* d_out, int out_size, void* d_ws, size_t ws_size,
                              hipStream_t stream) {
    const float* hidden = (const float*)d_in[0];
    const float* Wq = (const float*)d_in[1];
    const float* bq = (const float*)d_in[2];
    const float* Wk = (const float*)d_in[3];
    const float* bk = (const float*)d_in[4];
    const float* Wv = (const float*)d_in[5];
    const float* bvp = (const float*)d_in[6];
    const float* Wg = (const float*)d_in[7];
    const float* bg = (const float*)d_in[8];
    const float* Wo = (const float*)d_in[9];
    const float* bo = (const float*)d_in[10];
    const float* sinT = (const float*)d_in[11];
    const float* cosT = (const float*)d_in[12];
    // d_in[13] = decay_mask: unused (closed-form in-kernel)
    float* out = (float*)d_out;

    char* p = (char*)d_ws;
    bf16* hb = (bf16*)p;    p += (size_t)TT * HD * 2;
    bf16* Wcat = (bf16*)p;  p += (size_t)(HD + HD + VD + VD) * HD * 2;  // 12288 x 2048
    bf16* WoT = (bf16*)p;   p += (size_t)HD * VD * 2;
    bf16* qr = (bf16*)p;    p += (size_t)TT * HD * 2;
    bf16* kr = (bf16*)p;    p += (size_t)TT * HD * 2;
    bf16* vtmp = (bf16*)p;  p += (size_t)TT * VD * 2;
    bf16* vT = (bf16*)p;    p += (size_t)VD * TT * 2;
    bf16* sg = (bf16*)p;    p += (size_t)TT * VD * 2;
    float* po0 = (float*)p; p += (size_t)TT * VD * 4;
    float* po1 = (float*)p; p += (size_t)TT * VD * 4;
    float* pr0 = (float*)p; p += (size_t)NH * TT * 4;
    float* pr1 = (float*)p; p += (size_t)NH * TT * 4;
    bf16* gated = (bf16*)p; p += (size_t)TT * VD * 2;

    // 1) dtype conversions / weight transposes (into concatenated Wcat)
    f32_to_bf16_k<<<TT * HD / 1024, 256, 0, stream>>>(hidden, hb, TT * HD);
    transpose_tb_k<<<dim3(HD / 64, HD / 64), 256, 0, stream>>>(Wq, Wcat, HD, HD);
    transpose_tb_k<<<dim3(HD / 64, HD / 64), 256, 0, stream>>>(Wk, Wcat + (size_t)2048 * HD, HD, HD);
    transpose_tb_k<<<dim3(VD / 64, HD / 64), 256, 0, stream>>>(Wv, Wcat + (size_t)4096 * HD, HD, VD);
    transpose_tb_k<<<dim3(VD / 64, HD / 64), 256, 0, stream>>>(Wg, Wcat + (size_t)8192 * HD, HD, VD);
    transpose_tb_k<<<dim3(HD / 64, VD / 64), 256, 0, stream>>>(Wo, WoT, VD, HD);

    // 2) fused QKVG projection (8-phase 256x192, 512 balanced blocks), V transpose
    gemm_qkvg_k<<<512, 512, 0, stream>>>(hb, Wcat, bq, bk, bvp, bg, sinT, cosT,
                                         qr, kr, vtmp, sg);
    transpose_bf16_k<<<dim3(VD / 64, TT / 64), 256, 0, stream>>>(vtmp, vT);

    // 3) fused causal retention + PV (raw partials per kv-parity)
    retention_fused_k<<<dim3(8, 2, NH), 512, 0, stream>>>(qr, kr, vT, po0, po1, pr0, pr1);

    // 4) combine + groupnorm + gate, then output projection
    ln_gate_k<<<TT * NH / 4, 256, 0, stream>>>(po0, po1, pr0, pr1, sg, gated);
    gemm_out_k<<<256, 256, 0, stream>>>(gated, WoT, bo, out);
}

// Round 8
// 368.048 us; speedup vs baseline: 1.3486x; 1.0551x over previous
//
#include <hip/hip_runtime.h>
#include <hip/hip_bf16.h>

typedef __hip_bfloat16 bf16;
typedef __attribute__((ext_vector_type(8))) __bf16 bf16x8;
typedef __attribute__((ext_vector_type(4))) float f32x4;

constexpr int TT = 2048;   // sequence length
constexpr int HD = 2048;   // hidden dim
constexpr int VD = 4096;   // value dim
constexpr int KD = 128;    // key dim per head
constexpr int NH = 16;     // heads
constexpr int DH = 256;    // head dim of v
constexpr float K_SCALING = 0.08838834764831845f;  // 128^-0.5

__device__ __forceinline__ bf16 f2bf(float x) { return __float2bfloat16(x); }
__device__ __forceinline__ unsigned short f2bfu(float x) {
    bf16 b = __float2bfloat16(x);
    return *reinterpret_cast<unsigned short*>(&b);
}
__device__ __forceinline__ float bf2f(unsigned short u) {
    unsigned int x = ((unsigned int)u) << 16;
    return __uint_as_float(x);
}

// ---------------------------------------------------------------------------
// f32 -> bf16 linear convert (4 elems/thread)
// ---------------------------------------------------------------------------
__global__ __launch_bounds__(256) void f32_to_bf16_k(const float* __restrict__ in,
                                                     bf16* __restrict__ outb, int n) {
    int i = (blockIdx.x * 256 + threadIdx.x) * 4;
    if (i >= n) return;
    float4 v = *(const float4*)(in + i);
    bf16 tmp[4] = {f2bf(v.x), f2bf(v.y), f2bf(v.z), f2bf(v.w)};
    *(uint2*)(outb + i) = *(const uint2*)tmp;  // 8B store
}

// ---------------------------------------------------------------------------
// Batched weight transpose: all 5 weights in one launch (8192 flat 64x64 tiles)
// W[R][C] f32 -> WT[C][R] bf16
// ---------------------------------------------------------------------------
__global__ __launch_bounds__(256) void transpose_all_k(
    const float* __restrict__ Wq, const float* __restrict__ Wk,
    const float* __restrict__ Wv, const float* __restrict__ Wg,
    const float* __restrict__ Wo, bf16* __restrict__ Wcat, bf16* __restrict__ WoT)
{
    __shared__ unsigned short sT[64 * 72];
    int t2 = blockIdx.x;
    const float* src;
    bf16* dst;
    int R, C;
    if (t2 < 1024)      { src = Wq; dst = Wcat;                     R = 2048; C = 2048; }
    else if (t2 < 2048) { src = Wk; dst = Wcat + (size_t)2048 * HD; R = 2048; C = 2048; t2 -= 1024; }
    else if (t2 < 4096) { src = Wv; dst = Wcat + (size_t)4096 * HD; R = 2048; C = 4096; t2 -= 2048; }
    else if (t2 < 6144) { src = Wg; dst = Wcat + (size_t)8192 * HD; R = 2048; C = 4096; t2 -= 4096; }
    else                { src = Wo; dst = WoT;                      R = 4096; C = 2048; t2 -= 6144; }
    const int xt = C >> 6;
    const int x0 = (t2 % xt) * 64;  // col of W
    const int y0 = (t2 / xt) * 64;  // row of W

    const int t = threadIdx.x;
    {
        const int r = t >> 2;
        const int c0 = (t & 3) << 4;
        const float* s = src + (size_t)(y0 + r) * C + x0 + c0;
        unsigned short e[16];
#pragma unroll
        for (int j = 0; j < 4; ++j) {
            float4 v = *(const float4*)(s + j * 4);
            e[j * 4 + 0] = f2bfu(v.x);
            e[j * 4 + 1] = f2bfu(v.y);
            e[j * 4 + 2] = f2bfu(v.z);
            e[j * 4 + 3] = f2bfu(v.w);
        }
#pragma unroll
        for (int i = 0; i < 16; ++i) {
            const int c = c0 + i;
            sT[c * 72 + (r ^ (((c >> 3) & 7) << 3))] = e[i];
        }
    }
    __syncthreads();
    {
        const int c = t >> 2;
        const int r0 = (t & 3) << 4;
        const int xs = ((c >> 3) & 7) << 3;
#pragma unroll
        for (int s2 = 0; s2 < 16; s2 += 8) {
            bf16x8 v = *(const bf16x8*)&sT[c * 72 + ((r0 + s2) ^ xs)];
            *(bf16x8*)&dst[(size_t)(x0 + c) * R + y0 + r0 + s2] = v;
        }
    }
}

// ---------------------------------------------------------------------------
// bf16 transpose: in[T][VD] -> out[VD][T], 64x64 LDS tiles, b128 in/out
// ---------------------------------------------------------------------------
__global__ __launch_bounds__(256) void transpose_bf16_k(const bf16* __restrict__ in,
                                                        bf16* __restrict__ outb) {
    __shared__ unsigned short sT[64 * 72];
    const int tid = threadIdx.x;
    const int x0 = blockIdx.x * 64;  // d
    const int y0 = blockIdx.y * 64;  // t
    {
        const int lt = tid >> 2;
        const int c0 = (tid & 3) << 4;
        unsigned short e[16];
        *(bf16x8*)&e[0] = *(const bf16x8*)&in[(size_t)(y0 + lt) * VD + x0 + c0];
        *(bf16x8*)&e[8] = *(const bf16x8*)&in[(size_t)(y0 + lt) * VD + x0 + c0 + 8];
#pragma unroll
        for (int i = 0; i < 16; ++i) {
            const int c = c0 + i;
            sT[c * 72 + (lt ^ (((c >> 3) & 7) << 3))] = e[i];
        }
    }
    __syncthreads();
    {
        const int c = tid >> 2;
        const int r0 = (tid & 3) << 4;
        const int xs = ((c >> 3) & 7) << 3;
#pragma unroll
        for (int s2 = 0; s2 < 16; s2 += 8) {
            bf16x8 v = *(const bf16x8*)&sT[c * 72 + ((r0 + s2) ^ xs)];
            *(bf16x8*)&outb[(size_t)(x0 + c) * TT + y0 + r0 + s2] = v;
        }
    }
}

// ---------------------------------------------------------------------------
// Fused QKVG GEMM, 8-phase 256x192 schedule (BK=64, 2 K-tiles/iter).
// Grid 8 x 64 = 512 blocks = exactly 2 rounds on 256 CUs.
// Counted vmcnt(6) at end of ph3/ph7 (barrier-separated; verified tight).
// ---------------------------------------------------------------------------
#define GLL(gptr, lptr) __builtin_amdgcn_global_load_lds( \
    (const __attribute__((address_space(1))) void*)(gptr), \
    (__attribute__((address_space(3))) void*)(lptr), 16, 0, 0)

#define STA(bufs, u, k1) GLL(gA0 + (size_t)((u) * 64) * HD + (k1), sA + (bufs) + (u) * 4096 + tid * 8)
#define STB(bufs, u, k1) GLL(gB0 + (size_t)((u) * 64) * HD + (k1), sB + (bufs) + (u) * 4096 + tid * 8)

#define WAIT6 asm volatile("s_waitcnt vmcnt(6)" ::: "memory")
#define WAIT0V asm volatile("s_waitcnt vmcnt(0)" ::: "memory")
#define MEMF asm volatile("" ::: "memory")
#define BAR __builtin_amdgcn_s_barrier()

#define LDA(dst, cb, qm) \
    _Pragma("unroll") for (int mi = 0; mi < 4; ++mi) { \
        const int r_ = wr * 128 + (qm) * 64 + mi * 16 + lr; \
        _Pragma("unroll") for (int ks = 0; ks < 2; ++ks) \
            dst[mi][ks] = *(const bf16x8*)&sA[(cb) + r_ * 64 + (((ks * 4 + g) ^ (lr & 7)) << 3)]; \
    }

#define LDB01(dst, cb) \
    _Pragma("unroll") for (int ni = 0; ni < 2; ++ni) { \
        const int n_ = wcn * 48 + ni * 16 + lr; \
        _Pragma("unroll") for (int ks = 0; ks < 2; ++ks) \
            dst[ni][ks] = *(const bf16x8*)&sB[(cb) + n_ * 64 + (((ks * 4 + g) ^ (lr & 7)) << 3)]; \
    }

#define LDB2(dst, cb) { \
        const int n_ = wcn * 48 + 32 + lr; \
        _Pragma("unroll") for (int ks = 0; ks < 2; ++ks) \
            dst[ks] = *(const bf16x8*)&sB[(cb) + n_ * 64 + (((ks * 4 + g) ^ (lr & 7)) << 3)]; \
    }

#define Q00 __builtin_amdgcn_s_setprio(1); \
    _Pragma("unroll") for (int mi = 0; mi < 4; ++mi) \
        _Pragma("unroll") for (int ni = 0; ni < 2; ++ni) \
            _Pragma("unroll") for (int ks = 0; ks < 2; ++ks) \
                acc[mi][ni] = __builtin_amdgcn_mfma_f32_16x16x32_bf16(ra0[mi][ks], rb[ni][ks], acc[mi][ni], 0, 0, 0); \
    __builtin_amdgcn_s_setprio(0);
#define Q10 __builtin_amdgcn_s_setprio(1); \
    _Pragma("unroll") for (int mi = 0; mi < 4; ++mi) \
        _Pragma("unroll") for (int ni = 0; ni < 2; ++ni) \
            _Pragma("unroll") for (int ks = 0; ks < 2; ++ks) \
                acc[4 + mi][ni] = __builtin_amdgcn_mfma_f32_16x16x32_bf16(ra1[mi][ks], rb[ni][ks], acc[4 + mi][ni], 0, 0, 0); \
    __builtin_amdgcn_s_setprio(0);
#define Q11 __builtin_amdgcn_s_setprio(1); \
    _Pragma("unroll") for (int mi = 0; mi < 4; ++mi) \
        _Pragma("unroll") for (int ks = 0; ks < 2; ++ks) \
            acc[4 + mi][2] = __builtin_amdgcn_mfma_f32_16x16x32_bf16(ra1[mi][ks], rb2[ks], acc[4 + mi][2], 0, 0, 0); \
    __builtin_amdgcn_s_setprio(0);
#define Q01 __builtin_amdgcn_s_setprio(1); \
    _Pragma("unroll") for (int mi = 0; mi < 4; ++mi) \
        _Pragma("unroll") for (int ks = 0; ks < 2; ++ks) \
            acc[mi][2] = __builtin_amdgcn_mfma_f32_16x16x32_bf16(ra0[mi][ks], rb2[ks], acc[mi][2], 0, 0, 0); \
    __builtin_amdgcn_s_setprio(0);

__global__ __launch_bounds__(512, 2) void gemm_qkvg_k(
    const bf16* __restrict__ Ag, const bf16* __restrict__ Bg,
    const float* __restrict__ bq, const float* __restrict__ bk,
    const float* __restrict__ bvp, const float* __restrict__ bg,
    const float* __restrict__ sinT, const float* __restrict__ cosT,
    bf16* __restrict__ qr, bf16* __restrict__ kr,
    bf16* __restrict__ vtmp, bf16* __restrict__ sg)
{
    __shared__ unsigned short sA[2 * 256 * 64];  // 64 KB
    __shared__ unsigned short sB[2 * 192 * 64];  // 48 KB
    constexpr int BUFA = 16384, BUFB = 12288;

    const int tid = threadIdx.x;
    const int lane = tid & 63;
    const int w = tid >> 6;
    const int wr = w >> 2;
    const int wcn = w & 3;
    const int lr = lane & 15;
    const int g = lane >> 4;

    const int flat = blockIdx.x;
    const int swz = (flat & 7) * 64 + (flat >> 3);
    const int brow = (swz & 7) * 256;
    const int bcol = (swz >> 3) * 192;

    const bf16* gA0 = Ag + (size_t)(brow + (tid >> 3)) * HD + (((tid & 7) ^ ((tid >> 3) & 7)) << 3);
    const bf16* gB0 = Bg + (size_t)(bcol + (tid >> 3)) * HD + (((tid & 7) ^ ((tid >> 3) & 7)) << 3);

    f32x4 acc[8][3] = {};
    bf16x8 ra0[4][2], ra1[4][2], rb[2][2], rb2[2];

    STA(0, 0, 0); STA(0, 1, 0); STA(0, 2, 0); STA(0, 3, 0);
    STB(0, 0, 0); STB(0, 1, 0); STB(0, 2, 0);
    STA(BUFA, 0, 64); STA(BUFA, 1, 64); STA(BUFA, 2, 64); STA(BUFA, 3, 64);
    STB(BUFB, 0, 64); STB(BUFB, 1, 64);
    WAIT6; MEMF; BAR;

    for (int I = 0; I < 15; ++I) {
        const int kB1 = I * 128 + 64;
        const int kN2 = I * 128 + 128;
        const int kN3 = I * 128 + 192;
        LDA(ra0, 0, 0) LDB01(rb, 0)
        STB(BUFB, 2, kB1);
        MEMF; BAR; Q00 BAR;
        LDA(ra1, 0, 1)
        STA(0, 0, kN2); STA(0, 2, kN2);
        MEMF; BAR; Q10 BAR;
        LDB2(rb2, 0)
        STA(0, 1, kN2); STA(0, 3, kN2);
        MEMF; BAR; Q11 BAR;
        STB(0, 0, kN2); STB(0, 1, kN2);
        WAIT6; MEMF; BAR; Q01 BAR;
        LDA(ra0, BUFA, 0) LDB01(rb, BUFB)
        STB(0, 2, kN2);
        MEMF; BAR; Q00 BAR;
        LDA(ra1, BUFA, 1)
        STA(BUFA, 0, kN3); STA(BUFA, 2, kN3);
        MEMF; BAR; Q10 BAR;
        LDB2(rb2, BUFB)
        STA(BUFA, 1, kN3); STA(BUFA, 3, kN3);
        MEMF; BAR; Q11 BAR;
        STB(BUFB, 0, kN3); STB(BUFB, 1, kN3);
        WAIT6; MEMF; BAR; Q01 BAR;
    }
    {
        LDA(ra0, 0, 0) LDB01(rb, 0)
        STB(BUFB, 2, 1984);
        MEMF; BAR; Q00 BAR;
        LDA(ra1, 0, 1)
        MEMF; BAR; Q10 BAR;
        LDB2(rb2, 0)
        MEMF; BAR; Q11 BAR;
        WAIT0V; MEMF; BAR; Q01 BAR;
        LDA(ra0, BUFA, 0) LDB01(rb, BUFB)
        Q00
        LDA(ra1, BUFA, 1)
        Q10
        LDB2(rb2, BUFB)
        Q11
        Q01
    }

#pragma unroll
    for (int M = 0; M < 8; ++M) {
        const int row = brow + wr * 128 + (M >> 2) * 64 + (M & 3) * 16 + g * 4;
#pragma unroll
        for (int f = 0; f < 3; ++f) {
            const int colg = bcol + wcn * 48 + f * 16 + lr;
            if (colg < 4096) {
                const bool isK = (colg >= 2048);
                const int col = colg - (isK ? 2048 : 0);
                const float bvv = (isK ? bk : bq)[col];
                const float scale = isK ? K_SCALING : 1.f;
                bf16* outb = isK ? kr : qr;
                const int d = col & (KD - 1);
#pragma unroll
                for (int r = 0; r < 4; ++r) {
                    float v = (acc[M][f][r] + bvv) * scale;
                    float o = __shfl_xor(v, 1);
                    float rot = (col & 1) ? o : -o;
                    outb[(size_t)(row + r) * HD + col] =
                        f2bf(v * cosT[(row + r) * KD + d] + rot * sinT[(row + r) * KD + d]);
                }
            } else if (colg < 8192) {
                const int col = colg - 4096;
                const float bvv = bvp[col];
#pragma unroll
                for (int r = 0; r < 4; ++r)
                    vtmp[(size_t)(row + r) * VD + col] = f2bf(acc[M][f][r] + bvv);
            } else {
                const int col = colg - 8192;
                const float bvv = bg[col];
#pragma unroll
                for (int r = 0; r < 4; ++r) {
                    float v = acc[M][f][r] + bvv;
                    sg[(size_t)(row + r) * VD + col] = f2bf(v / (1.f + __expf(-v)));
                }
            }
        }
    }
}

// ---------------------------------------------------------------------------
// Output GEMM: out[2048,2048] = gated[2048,4096] @ WoT[2048,4096]^T + bo
// ---------------------------------------------------------------------------
__global__ __launch_bounds__(256) void gemm_out_k(
    const bf16* __restrict__ Ag, const bf16* __restrict__ Bg,
    const float* __restrict__ bias, float* __restrict__ outf)
{
    __shared__ unsigned short sOA[128 * 32];
    __shared__ unsigned short sOB[128 * 32];

    const int flat = blockIdx.x;
    const int swz = (flat & 7) * 32 + (flat >> 3);
    const int brow = (swz & 15) * 128;
    const int bcol = (swz >> 4) * 128;

    const int tid = threadIdx.x;
    const int lane = tid & 63;
    const int wid = tid >> 6;
    const int wr = wid >> 1, wc = wid & 1;

    f32x4 acc[4][4] = {};

    const int lr = lane & 15;
    const int lk = (lane >> 4) << 3;
    const int r0 = tid >> 2;
    const int c0 = (tid & 3) << 3;
    const int ldsw = (tid & 192) << 3;

    for (int k0 = 0; k0 < VD; k0 += 32) {
        const bf16* gA = Ag + (size_t)(brow + r0) * VD + k0 + c0;
        const bf16* gB = Bg + (size_t)(bcol + r0) * VD + k0 + c0;
        GLL(gA, sOA + ldsw);
        GLL(gB, sOB + ldsw);
        GLL(gA + 64 * VD, sOA + 2048 + ldsw);
        GLL(gB + 64 * VD, sOB + 2048 + ldsw);
        __syncthreads();

        bf16x8 af[4], bv[4];
#pragma unroll
        for (int mi = 0; mi < 4; ++mi)
            af[mi] = *(const bf16x8*)&sOA[(wr * 64 + mi * 16 + lr) * 32 + lk];
#pragma unroll
        for (int ni = 0; ni < 4; ++ni)
            bv[ni] = *(const bf16x8*)&sOB[(wc * 64 + ni * 16 + lr) * 32 + lk];
#pragma unroll
        for (int mi = 0; mi < 4; ++mi)
#pragma unroll
            for (int ni = 0; ni < 4; ++ni)
                acc[mi][ni] = __builtin_amdgcn_mfma_f32_16x16x32_bf16(af[mi], bv[ni], acc[mi][ni], 0, 0, 0);
        __syncthreads();
    }

    const int row0 = brow + wr * 64 + ((lane >> 4) << 2);
    const int col0 = bcol + wc * 64 + lr;
#pragma unroll
    for (int mi = 0; mi < 4; ++mi) {
#pragma unroll
        for (int ni = 0; ni < 4; ++ni) {
            const int col = col0 + ni * 16;
            const float bvv = bias[col];
#pragma unroll
            for (int r = 0; r < 4; ++r) {
                const int row = row0 + mi * 16 + r;
                outf[(size_t)row * HD + col] = acc[mi][ni][r] + bvv;
            }
        }
    }
}

// ---------------------------------------------------------------------------
// Fused causal retention + PV; mask factorized a(s)*b(t), a via recurrence.
// Partials written bf16. Grid: (8, 2, 16) = 256 blocks x 512 threads.
// ---------------------------------------------------------------------------
__global__ __launch_bounds__(512) void retention_fused_k(
    const bf16* __restrict__ qr, const bf16* __restrict__ kr,
    const bf16* __restrict__ vT,
    bf16* __restrict__ po0, bf16* __restrict__ po1,
    float* __restrict__ pr0, float* __restrict__ pr1)
{
    __shared__ unsigned short P_lds[128 * 128];
    __shared__ float rsum_lds[4][128];

    const int tid = threadIdx.x;
    const int lane = tid & 63;
    const int wid = tid >> 6;
    const int wr64 = (wid >> 2) * 64;
    const int wc = wid & 3;
    const int lr = lane & 15;
    const int g = lane >> 4;
    const int lk = g << 3;
    const int pidx = blockIdx.x;
    const int parity = blockIdx.y;
    const int h = blockIdx.z;

    const float decay = logf(1.f - exp2f(-5.f - (float)h));
    bf16* __restrict__ po = parity ? po1 : po0;
    float* __restrict__ pr = parity ? pr1 : pr0;

    const int swzA = (lr & 7) << 3;

    const float bfac0 = __expf(decay * (float)(-(wc * 32 + lr)));
    const float bfac1 = __expf(decay * (float)(-(wc * 32 + 16 + lr)));
    const float astep = __expf(decay * -256.f);   // per-tile multiplicative update

    for (int sec = 0; sec < 2; ++sec) {
        const int qb = sec ? (15 - pidx) : pidx;
        const int qrow0 = qb * 128;

        bf16x8 af[4][4];
#pragma unroll
        for (int mi = 0; mi < 4; ++mi)
#pragma unroll
            for (int ks = 0; ks < 4; ++ks)
                af[mi][ks] = *(const bf16x8*)&qr[(size_t)(qrow0 + wr64 + mi * 16 + lr) * HD +
                                                 h * KD + ks * 32 + lk];

        f32x4 acc_o[4][4] = {};
        float rs[4][4] = {};
        // a(s) init for first tile (t0 = parity*128); recurrence per tile
        float aexp[4][4];
#pragma unroll
        for (int mi = 0; mi < 4; ++mi)
#pragma unroll
            for (int r = 0; r < 4; ++r) {
                const int row_l = wr64 + mi * 16 + g * 4 + r;
                aexp[mi][r] = __expf(decay * (float)(qrow0 + row_l - parity * 128));
            }

        for (int tb = parity; tb <= qb; tb += 2) {
            const int t0 = tb * 128;

            f32x4 acc_p[4][2] = {};
#pragma unroll
            for (int ks = 0; ks < 4; ++ks) {
                const bf16x8 b0 = *(const bf16x8*)&kr[(size_t)(t0 + wc * 32 + lr) * HD +
                                                      h * KD + ks * 32 + lk];
                const bf16x8 b1 = *(const bf16x8*)&kr[(size_t)(t0 + wc * 32 + 16 + lr) * HD +
                                                      h * KD + ks * 32 + lk];
#pragma unroll
                for (int mi = 0; mi < 4; ++mi) {
                    acc_p[mi][0] = __builtin_amdgcn_mfma_f32_16x16x32_bf16(af[mi][ks], b0, acc_p[mi][0], 0, 0, 0);
                    acc_p[mi][1] = __builtin_amdgcn_mfma_f32_16x16x32_bf16(af[mi][ks], b1, acc_p[mi][1], 0, 0, 0);
                }
            }

#pragma unroll
            for (int mi = 0; mi < 4; ++mi) {
#pragma unroll
                for (int r = 0; r < 4; ++r) {
                    const int rl = g * 4 + r;
                    const int row_l = wr64 + mi * 16 + rl;
                    const int srel = qrow0 + row_l - t0;
                    const float a = aexp[mi][r];
                    const float p0 = (wc * 32 + lr <= srel) ? acc_p[mi][0][r] * a * bfac0 : 0.f;
                    const float p1 = (wc * 32 + 16 + lr <= srel) ? acc_p[mi][1][r] * a * bfac1 : 0.f;
                    const int sw = (rl & 7) << 3;
                    P_lds[row_l * 128 + ((wc * 32 + lr) ^ sw)] = f2bfu(p0);
                    P_lds[row_l * 128 + ((wc * 32 + 16 + lr) ^ sw)] = f2bfu(p1);
                    rs[mi][r] += p0 + p1;
                    aexp[mi][r] = a * astep;
                }
            }
            __syncthreads();

#pragma unroll
            for (int ks2 = 0; ks2 < 4; ++ks2) {
                bf16x8 a2[4], b2[4];
#pragma unroll
                for (int mi = 0; mi < 4; ++mi)
                    a2[mi] = *(const bf16x8*)&P_lds[(wr64 + mi * 16 + lr) * 128 +
                                                    ((ks2 * 32 + lk) ^ swzA)];
#pragma unroll
                for (int ni = 0; ni < 4; ++ni)
                    b2[ni] = *(const bf16x8*)&vT[(size_t)(h * DH + wc * 64 + ni * 16 + lr) * TT +
                                                 t0 + ks2 * 32 + lk];
#pragma unroll
                for (int mi = 0; mi < 4; ++mi)
#pragma unroll
                    for (int ni = 0; ni < 4; ++ni)
                        acc_o[mi][ni] = __builtin_amdgcn_mfma_f32_16x16x32_bf16(a2[mi], b2[ni], acc_o[mi][ni], 0, 0, 0);
            }
            __syncthreads();
        }

#pragma unroll
        for (int mi = 0; mi < 4; ++mi)
#pragma unroll
            for (int r = 0; r < 4; ++r) {
                float v = rs[mi][r];
                v += __shfl_xor(v, 1);
                v += __shfl_xor(v, 2);
                v += __shfl_xor(v, 4);
                v += __shfl_xor(v, 8);
                if (lr == 0) rsum_lds[wc][wr64 + mi * 16 + g * 4 + r] = v;
            }
        __syncthreads();
        if (tid < 128)
            pr[(size_t)h * TT + qrow0 + tid] =
                rsum_lds[0][tid] + rsum_lds[1][tid] + rsum_lds[2][tid] + rsum_lds[3][tid];

#pragma unroll
        for (int mi = 0; mi < 4; ++mi)
#pragma unroll
            for (int ni = 0; ni < 4; ++ni)
#pragma unroll
                for (int r = 0; r < 4; ++r) {
                    const int row_l = wr64 + mi * 16 + g * 4 + r;
                    const int col = wc * 64 + ni * 16 + lr;
                    po[(size_t)(qrow0 + row_l) * VD + h * DH + col] = f2bf(acc_o[mi][ni][r]);
                }
        __syncthreads();
    }
}

// ---------------------------------------------------------------------------
// Combine bf16 parity partials -> scale -> LN(256) -> silu-gate (bf16)
// ---------------------------------------------------------------------------
__global__ __launch_bounds__(256) void ln_gate_k(const bf16* __restrict__ po0,
                                                 const bf16* __restrict__ po1,
                                                 const float* __restrict__ pr0,
                                                 const float* __restrict__ pr1,
                                                 const bf16* __restrict__ sg,
                                                 bf16* __restrict__ gated) {
    const int tid = threadIdx.x;
    const int lane = tid & 63;
    const size_t ridx = (size_t)blockIdx.x * 4 + (tid >> 6);  // = s*16 + h
    const int h = (int)(ridx & 15);
    const int s = (int)(ridx >> 4);

    const float decay = logf(1.f - exp2f(-5.f - (float)h));
    const float Sm = -expm1f(decay * (float)(s + 1)) * exp2f(5.f + (float)h);
    const float norm = rsqrtf(Sm);
    const float raw = pr0[(size_t)h * TT + s] + pr1[(size_t)h * TT + s];
    const float scale = norm / fmaxf(1.f, fabsf(raw * norm));

    unsigned short ua[4], ub[4];
    *(uint2*)ua = *(const uint2*)(po0 + ridx * 256 + lane * 4);
    *(uint2*)ub = *(const uint2*)(po1 + ridx * 256 + lane * 4);
    float vv[4];
#pragma unroll
    for (int i = 0; i < 4; ++i)
        vv[i] = (bf2f(ua[i]) + bf2f(ub[i])) * scale;
    float sm = vv[0] + vv[1] + vv[2] + vv[3];
    float sq = vv[0] * vv[0] + vv[1] * vv[1] + vv[2] * vv[2] + vv[3] * vv[3];
#pragma unroll
    for (int o = 1; o < 64; o <<= 1) {
        sm += __shfl_xor(sm, o);
        sq += __shfl_xor(sq, o);
    }
    const float mu = sm * (1.f / 256.f);
    const float var = sq * (1.f / 256.f) - mu * mu;
    const float rstd = rsqrtf(var + 1e-6f);
    const bf16* sgp = sg + ridx * 256 + lane * 4;
    bf16* gp = gated + ridx * 256 + lane * 4;
    bf16 ob[4];
#pragma unroll
    for (int i = 0; i < 4; ++i)
        ob[i] = f2bf((vv[i] - mu) * rstd * __bfloat162float(sgp[i]));
    *(uint2*)gp = *(const uint2*)ob;
}

// ---------------------------------------------------------------------------
extern "C" void kernel_launch(void* const* d_in, const int* in_sizes, int n_in,
                              void* d_out, int out_size, void* d_ws, size_t ws_size,
                              hipStream_t stream) {
    const float* hidden = (const float*)d_in[0];
    const float* Wq = (const float*)d_in[1];
    const float* bq = (const float*)d_in[2];
    const float* Wk = (const float*)d_in[3];
    const float* bk = (const float*)d_in[4];
    const float* Wv = (const float*)d_in[5];
    const float* bvp = (const float*)d_in[6];
    const float* Wg = (const float*)d_in[7];
    const float* bg = (const float*)d_in[8];
    const float* Wo = (const float*)d_in[9];
    const float* bo = (const float*)d_in[10];
    const float* sinT = (const float*)d_in[11];
    const float* cosT = (const float*)d_in[12];
    float* out = (float*)d_out;

    char* p = (char*)d_ws;
    bf16* hb = (bf16*)p;    p += (size_t)TT * HD * 2;
    bf16* Wcat = (bf16*)p;  p += (size_t)(HD + HD + VD + VD) * HD * 2;
    bf16* WoT = (bf16*)p;   p += (size_t)HD * VD * 2;
    bf16* qr = (bf16*)p;    p += (size_t)TT * HD * 2;
    bf16* kr = (bf16*)p;    p += (size_t)TT * HD * 2;
    bf16* vtmp = (bf16*)p;  p += (size_t)TT * VD * 2;
    bf16* vT = (bf16*)p;    p += (size_t)VD * TT * 2;
    bf16* sg = (bf16*)p;    p += (size_t)TT * VD * 2;
    bf16* po0 = (bf16*)p;   p += (size_t)TT * VD * 2;
    bf16* po1 = (bf16*)p;   p += (size_t)TT * VD * 2;
    float* pr0 = (float*)p; p += (size_t)NH * TT * 4;
    float* pr1 = (float*)p; p += (size_t)NH * TT * 4;
    bf16* gated = (bf16*)p; p += (size_t)TT * VD * 2;

    // 1) conversions + all weight transposes (single launch)
    f32_to_bf16_k<<<TT * HD / 1024, 256, 0, stream>>>(hidden, hb, TT * HD);
    transpose_all_k<<<8192, 256, 0, stream>>>(Wq, Wk, Wv, Wg, Wo, Wcat, WoT);

    // 2) fused QKVG projection (8-phase 256x192), V transpose
    gemm_qkvg_k<<<512, 512, 0, stream>>>(hb, Wcat, bq, bk, bvp, bg, sinT, cosT,
                                         qr, kr, vtmp, sg);
    transpose_bf16_k<<<dim3(VD / 64, TT / 64), 256, 0, stream>>>(vtmp, vT);

    // 3) fused causal retention + PV (bf16 partials per kv-parity)
    retention_fused_k<<<dim3(8, 2, NH), 512, 0, stream>>>(qr, kr, vT, po0, po1, pr0, pr1);

    // 4) combine + groupnorm + gate, then output projection
    ln_gate_k<<<TT * NH / 4, 256, 0, stream>>>(po0, po1, pr0, pr1, sg, gated);
    gemm_out_k<<<256, 256, 0, stream>>>(gated, WoT, bo, out);
}

// Round 9
// 333.911 us; speedup vs baseline: 1.4865x; 1.1022x over previous
//
#include <hip/hip_runtime.h>
#include <hip/hip_bf16.h>

typedef __hip_bfloat16 bf16;
typedef __attribute__((ext_vector_type(8))) __bf16 bf16x8;
typedef __attribute__((ext_vector_type(4))) float f32x4;

constexpr int TT = 2048;   // sequence length
constexpr int HD = 2048;   // hidden dim
constexpr int VD = 4096;   // value dim
constexpr int KD = 128;    // key dim per head
constexpr int NH = 16;     // heads
constexpr int DH = 256;    // head dim of v
constexpr float K_SCALING = 0.08838834764831845f;  // 128^-0.5

__device__ __forceinline__ bf16 f2bf(float x) { return __float2bfloat16(x); }
__device__ __forceinline__ unsigned short f2bfu(float x) {
    bf16 b = __float2bfloat16(x);
    return *reinterpret_cast<unsigned short*>(&b);
}
__device__ __forceinline__ float bf2f(unsigned short u) {
    unsigned int x = ((unsigned int)u) << 16;
    return __uint_as_float(x);
}

// ---------------------------------------------------------------------------
// Batched: all 5 weight transposes (8192 tiles) + hidden f32->bf16 (512 blocks)
// ---------------------------------------------------------------------------
__global__ __launch_bounds__(256) void transpose_all_k(
    const float* __restrict__ Wq, const float* __restrict__ Wk,
    const float* __restrict__ Wv, const float* __restrict__ Wg,
    const float* __restrict__ Wo, bf16* __restrict__ Wcat, bf16* __restrict__ WoT,
    const float* __restrict__ hidden, bf16* __restrict__ hb)
{
    __shared__ unsigned short sT[64 * 72];
    int t2 = blockIdx.x;
    if (t2 >= 8192) {
        // hidden convert: 512 blocks x 8192 elems
        const int b = t2 - 8192;
        const size_t base = (size_t)b * 8192;
#pragma unroll
        for (int j = 0; j < 8; ++j) {
            const size_t i = base + j * 1024 + threadIdx.x * 4;
            float4 v = *(const float4*)(hidden + i);
            bf16 tmp[4] = {f2bf(v.x), f2bf(v.y), f2bf(v.z), f2bf(v.w)};
            *(uint2*)(hb + i) = *(const uint2*)tmp;
        }
        return;
    }
    const float* src;
    bf16* dst;
    int R, C;
    if (t2 < 1024)      { src = Wq; dst = Wcat;                     R = 2048; C = 2048; }
    else if (t2 < 2048) { src = Wk; dst = Wcat + (size_t)2048 * HD; R = 2048; C = 2048; t2 -= 1024; }
    else if (t2 < 4096) { src = Wv; dst = Wcat + (size_t)4096 * HD; R = 2048; C = 4096; t2 -= 2048; }
    else if (t2 < 6144) { src = Wg; dst = Wcat + (size_t)8192 * HD; R = 2048; C = 4096; t2 -= 4096; }
    else                { src = Wo; dst = WoT;                      R = 4096; C = 2048; t2 -= 6144; }
    const int xt = C >> 6;
    const int x0 = (t2 % xt) * 64;
    const int y0 = (t2 / xt) * 64;

    const int t = threadIdx.x;
    {
        const int r = t >> 2;
        const int c0 = (t & 3) << 4;
        const float* s = src + (size_t)(y0 + r) * C + x0 + c0;
        unsigned short e[16];
#pragma unroll
        for (int j = 0; j < 4; ++j) {
            float4 v = *(const float4*)(s + j * 4);
            e[j * 4 + 0] = f2bfu(v.x);
            e[j * 4 + 1] = f2bfu(v.y);
            e[j * 4 + 2] = f2bfu(v.z);
            e[j * 4 + 3] = f2bfu(v.w);
        }
#pragma unroll
        for (int i = 0; i < 16; ++i) {
            const int c = c0 + i;
            sT[c * 72 + (r ^ (((c >> 3) & 7) << 3))] = e[i];
        }
    }
    __syncthreads();
    {
        const int c = t >> 2;
        const int r0 = (t & 3) << 4;
        const int xs = ((c >> 3) & 7) << 3;
#pragma unroll
        for (int s2 = 0; s2 < 16; s2 += 8) {
            bf16x8 v = *(const bf16x8*)&sT[c * 72 + ((r0 + s2) ^ xs)];
            *(bf16x8*)&dst[(size_t)(x0 + c) * R + y0 + r0 + s2] = v;
        }
    }
}

// ---------------------------------------------------------------------------
// bf16 transpose: in[T][VD] -> out[VD][T], 64x64 LDS tiles, b128 in/out
// ---------------------------------------------------------------------------
__global__ __launch_bounds__(256) void transpose_bf16_k(const bf16* __restrict__ in,
                                                        bf16* __restrict__ outb) {
    __shared__ unsigned short sT[64 * 72];
    const int tid = threadIdx.x;
    const int x0 = blockIdx.x * 64;  // d
    const int y0 = blockIdx.y * 64;  // t
    {
        const int lt = tid >> 2;
        const int c0 = (tid & 3) << 4;
        unsigned short e[16];
        *(bf16x8*)&e[0] = *(const bf16x8*)&in[(size_t)(y0 + lt) * VD + x0 + c0];
        *(bf16x8*)&e[8] = *(const bf16x8*)&in[(size_t)(y0 + lt) * VD + x0 + c0 + 8];
#pragma unroll
        for (int i = 0; i < 16; ++i) {
            const int c = c0 + i;
            sT[c * 72 + (lt ^ (((c >> 3) & 7) << 3))] = e[i];
        }
    }
    __syncthreads();
    {
        const int c = tid >> 2;
        const int r0 = (tid & 3) << 4;
        const int xs = ((c >> 3) & 7) << 3;
#pragma unroll
        for (int s2 = 0; s2 < 16; s2 += 8) {
            bf16x8 v = *(const bf16x8*)&sT[c * 72 + ((r0 + s2) ^ xs)];
            *(bf16x8*)&outb[(size_t)(x0 + c) * TT + y0 + r0 + s2] = v;
        }
    }
}

// ---------------------------------------------------------------------------
// Fused QKVG GEMM, 8-phase 256x192 schedule (BK=64, 2 K-tiles/iter).
// ---------------------------------------------------------------------------
#define GLL(gptr, lptr) __builtin_amdgcn_global_load_lds( \
    (const __attribute__((address_space(1))) void*)(gptr), \
    (__attribute__((address_space(3))) void*)(lptr), 16, 0, 0)

#define STA(bufs, u, k1) GLL(gA0 + (size_t)((u) * 64) * HD + (k1), sA + (bufs) + (u) * 4096 + tid * 8)
#define STB(bufs, u, k1) GLL(gB0 + (size_t)((u) * 64) * HD + (k1), sB + (bufs) + (u) * 4096 + tid * 8)

#define WAIT6 asm volatile("s_waitcnt vmcnt(6)" ::: "memory")
#define WAIT0V asm volatile("s_waitcnt vmcnt(0)" ::: "memory")
#define MEMF asm volatile("" ::: "memory")
#define BAR __builtin_amdgcn_s_barrier()

#define LDA(dst, cb, qm) \
    _Pragma("unroll") for (int mi = 0; mi < 4; ++mi) { \
        const int r_ = wr * 128 + (qm) * 64 + mi * 16 + lr; \
        _Pragma("unroll") for (int ks = 0; ks < 2; ++ks) \
            dst[mi][ks] = *(const bf16x8*)&sA[(cb) + r_ * 64 + (((ks * 4 + g) ^ (lr & 7)) << 3)]; \
    }

#define LDB01(dst, cb) \
    _Pragma("unroll") for (int ni = 0; ni < 2; ++ni) { \
        const int n_ = wcn * 48 + ni * 16 + lr; \
        _Pragma("unroll") for (int ks = 0; ks < 2; ++ks) \
            dst[ni][ks] = *(const bf16x8*)&sB[(cb) + n_ * 64 + (((ks * 4 + g) ^ (lr & 7)) << 3)]; \
    }

#define LDB2(dst, cb) { \
        const int n_ = wcn * 48 + 32 + lr; \
        _Pragma("unroll") for (int ks = 0; ks < 2; ++ks) \
            dst[ks] = *(const bf16x8*)&sB[(cb) + n_ * 64 + (((ks * 4 + g) ^ (lr & 7)) << 3)]; \
    }

#define Q00 __builtin_amdgcn_s_setprio(1); \
    _Pragma("unroll") for (int mi = 0; mi < 4; ++mi) \
        _Pragma("unroll") for (int ni = 0; ni < 2; ++ni) \
            _Pragma("unroll") for (int ks = 0; ks < 2; ++ks) \
                acc[mi][ni] = __builtin_amdgcn_mfma_f32_16x16x32_bf16(ra0[mi][ks], rb[ni][ks], acc[mi][ni], 0, 0, 0); \
    __builtin_amdgcn_s_setprio(0);
#define Q10 __builtin_amdgcn_s_setprio(1); \
    _Pragma("unroll") for (int mi = 0; mi < 4; ++mi) \
        _Pragma("unroll") for (int ni = 0; ni < 2; ++ni) \
            _Pragma("unroll") for (int ks = 0; ks < 2; ++ks) \
                acc[4 + mi][ni] = __builtin_amdgcn_mfma_f32_16x16x32_bf16(ra1[mi][ks], rb[ni][ks], acc[4 + mi][ni], 0, 0, 0); \
    __builtin_amdgcn_s_setprio(0);
#define Q11 __builtin_amdgcn_s_setprio(1); \
    _Pragma("unroll") for (int mi = 0; mi < 4; ++mi) \
        _Pragma("unroll") for (int ks = 0; ks < 2; ++ks) \
            acc[4 + mi][2] = __builtin_amdgcn_mfma_f32_16x16x32_bf16(ra1[mi][ks], rb2[ks], acc[4 + mi][2], 0, 0, 0); \
    __builtin_amdgcn_s_setprio(0);
#define Q01 __builtin_amdgcn_s_setprio(1); \
    _Pragma("unroll") for (int mi = 0; mi < 4; ++mi) \
        _Pragma("unroll") for (int ks = 0; ks < 2; ++ks) \
            acc[mi][2] = __builtin_amdgcn_mfma_f32_16x16x32_bf16(ra0[mi][ks], rb2[ks], acc[mi][2], 0, 0, 0); \
    __builtin_amdgcn_s_setprio(0);

__global__ __launch_bounds__(512, 2) void gemm_qkvg_k(
    const bf16* __restrict__ Ag, const bf16* __restrict__ Bg,
    const float* __restrict__ bq, const float* __restrict__ bk,
    const float* __restrict__ bvp, const float* __restrict__ bg,
    const float* __restrict__ sinT, const float* __restrict__ cosT,
    bf16* __restrict__ qr, bf16* __restrict__ kr,
    bf16* __restrict__ vtmp, bf16* __restrict__ sg)
{
    __shared__ unsigned short sA[2 * 256 * 64];
    __shared__ unsigned short sB[2 * 192 * 64];
    constexpr int BUFA = 16384, BUFB = 12288;

    const int tid = threadIdx.x;
    const int lane = tid & 63;
    const int w = tid >> 6;
    const int wr = w >> 2;
    const int wcn = w & 3;
    const int lr = lane & 15;
    const int g = lane >> 4;

    const int flat = blockIdx.x;
    const int swz = (flat & 7) * 64 + (flat >> 3);
    const int brow = (swz & 7) * 256;
    const int bcol = (swz >> 3) * 192;

    const bf16* gA0 = Ag + (size_t)(brow + (tid >> 3)) * HD + (((tid & 7) ^ ((tid >> 3) & 7)) << 3);
    const bf16* gB0 = Bg + (size_t)(bcol + (tid >> 3)) * HD + (((tid & 7) ^ ((tid >> 3) & 7)) << 3);

    f32x4 acc[8][3] = {};
    bf16x8 ra0[4][2], ra1[4][2], rb[2][2], rb2[2];

    STA(0, 0, 0); STA(0, 1, 0); STA(0, 2, 0); STA(0, 3, 0);
    STB(0, 0, 0); STB(0, 1, 0); STB(0, 2, 0);
    STA(BUFA, 0, 64); STA(BUFA, 1, 64); STA(BUFA, 2, 64); STA(BUFA, 3, 64);
    STB(BUFB, 0, 64); STB(BUFB, 1, 64);
    WAIT6; MEMF; BAR;

    for (int I = 0; I < 15; ++I) {
        const int kB1 = I * 128 + 64;
        const int kN2 = I * 128 + 128;
        const int kN3 = I * 128 + 192;
        LDA(ra0, 0, 0) LDB01(rb, 0)
        STB(BUFB, 2, kB1);
        MEMF; BAR; Q00 BAR;
        LDA(ra1, 0, 1)
        STA(0, 0, kN2); STA(0, 2, kN2);
        MEMF; BAR; Q10 BAR;
        LDB2(rb2, 0)
        STA(0, 1, kN2); STA(0, 3, kN2);
        MEMF; BAR; Q11 BAR;
        STB(0, 0, kN2); STB(0, 1, kN2);
        WAIT6; MEMF; BAR; Q01 BAR;
        LDA(ra0, BUFA, 0) LDB01(rb, BUFB)
        STB(0, 2, kN2);
        MEMF; BAR; Q00 BAR;
        LDA(ra1, BUFA, 1)
        STA(BUFA, 0, kN3); STA(BUFA, 2, kN3);
        MEMF; BAR; Q10 BAR;
        LDB2(rb2, BUFB)
        STA(BUFA, 1, kN3); STA(BUFA, 3, kN3);
        MEMF; BAR; Q11 BAR;
        STB(BUFB, 0, kN3); STB(BUFB, 1, kN3);
        WAIT6; MEMF; BAR; Q01 BAR;
    }
    {
        LDA(ra0, 0, 0) LDB01(rb, 0)
        STB(BUFB, 2, 1984);
        MEMF; BAR; Q00 BAR;
        LDA(ra1, 0, 1)
        MEMF; BAR; Q10 BAR;
        LDB2(rb2, 0)
        MEMF; BAR; Q11 BAR;
        WAIT0V; MEMF; BAR; Q01 BAR;
        LDA(ra0, BUFA, 0) LDB01(rb, BUFB)
        Q00
        LDA(ra1, BUFA, 1)
        Q10
        LDB2(rb2, BUFB)
        Q11
        Q01
    }

#pragma unroll
    for (int M = 0; M < 8; ++M) {
        const int row = brow + wr * 128 + (M >> 2) * 64 + (M & 3) * 16 + g * 4;
#pragma unroll
        for (int f = 0; f < 3; ++f) {
            const int colg = bcol + wcn * 48 + f * 16 + lr;
            if (colg < 4096) {
                const bool isK = (colg >= 2048);
                const int col = colg - (isK ? 2048 : 0);
                const float bvv = (isK ? bk : bq)[col];
                const float scale = isK ? K_SCALING : 1.f;
                bf16* outb = isK ? kr : qr;
                const int d = col & (KD - 1);
#pragma unroll
                for (int r = 0; r < 4; ++r) {
                    float v = (acc[M][f][r] + bvv) * scale;
                    float o = __shfl_xor(v, 1);
                    float rot = (col & 1) ? o : -o;
                    outb[(size_t)(row + r) * HD + col] =
                        f2bf(v * cosT[(row + r) * KD + d] + rot * sinT[(row + r) * KD + d]);
                }
            } else if (colg < 8192) {
                const int col = colg - 4096;
                const float bvv = bvp[col];
#pragma unroll
                for (int r = 0; r < 4; ++r)
                    vtmp[(size_t)(row + r) * VD + col] = f2bf(acc[M][f][r] + bvv);
            } else {
                const int col = colg - 8192;
                const float bvv = bg[col];
#pragma unroll
                for (int r = 0; r < 4; ++r) {
                    float v = acc[M][f][r] + bvv;
                    sg[(size_t)(row + r) * VD + col] = f2bf(v / (1.f + __expf(-v)));
                }
            }
        }
    }
}

// ---------------------------------------------------------------------------
// Output GEMM partials: K-split x2. outp[z][2048][2048] = gated @ WoT^T over
// K-range [z*2048, (z+1)*2048). Grid (256, 2) = 512 blocks = 2/CU.
// ---------------------------------------------------------------------------
__global__ __launch_bounds__(256) void gemm_out_k(
    const bf16* __restrict__ Ag, const bf16* __restrict__ Bg,
    float* __restrict__ outp)
{
    __shared__ unsigned short sOA[128 * 32];
    __shared__ unsigned short sOB[128 * 32];

    const int flat = blockIdx.x;
    const int swz = (flat & 7) * 32 + (flat >> 3);
    const int brow = (swz & 15) * 128;
    const int bcol = (swz >> 4) * 128;
    const int kbase = blockIdx.y * 2048;

    const int tid = threadIdx.x;
    const int lane = tid & 63;
    const int wid = tid >> 6;
    const int wr = wid >> 1, wc = wid & 1;

    f32x4 acc[4][4] = {};

    const int lr = lane & 15;
    const int lk = (lane >> 4) << 3;
    const int r0 = tid >> 2;
    const int c0 = (tid & 3) << 3;
    const int ldsw = (tid & 192) << 3;

    for (int k0 = kbase; k0 < kbase + 2048; k0 += 32) {
        const bf16* gA = Ag + (size_t)(brow + r0) * VD + k0 + c0;
        const bf16* gB = Bg + (size_t)(bcol + r0) * VD + k0 + c0;
        GLL(gA, sOA + ldsw);
        GLL(gB, sOB + ldsw);
        GLL(gA + 64 * VD, sOA + 2048 + ldsw);
        GLL(gB + 64 * VD, sOB + 2048 + ldsw);
        __syncthreads();

        bf16x8 af[4], bv[4];
#pragma unroll
        for (int mi = 0; mi < 4; ++mi)
            af[mi] = *(const bf16x8*)&sOA[(wr * 64 + mi * 16 + lr) * 32 + lk];
#pragma unroll
        for (int ni = 0; ni < 4; ++ni)
            bv[ni] = *(const bf16x8*)&sOB[(wc * 64 + ni * 16 + lr) * 32 + lk];
#pragma unroll
        for (int mi = 0; mi < 4; ++mi)
#pragma unroll
            for (int ni = 0; ni < 4; ++ni)
                acc[mi][ni] = __builtin_amdgcn_mfma_f32_16x16x32_bf16(af[mi], bv[ni], acc[mi][ni], 0, 0, 0);
        __syncthreads();
    }

    float* op = outp + (size_t)blockIdx.y * TT * HD;
    const int row0 = brow + wr * 64 + ((lane >> 4) << 2);
    const int col0 = bcol + wc * 64 + lr;
#pragma unroll
    for (int mi = 0; mi < 4; ++mi) {
#pragma unroll
        for (int ni = 0; ni < 4; ++ni) {
            const int col = col0 + ni * 16;
#pragma unroll
            for (int r = 0; r < 4; ++r) {
                const int row = row0 + mi * 16 + r;
                op[(size_t)row * HD + col] = acc[mi][ni][r];
            }
        }
    }
}

// ---------------------------------------------------------------------------
// Combine K-split partials + bias -> final f32 out
// ---------------------------------------------------------------------------
__global__ __launch_bounds__(256) void combine_out_k(const float* __restrict__ outp,
                                                     const float* __restrict__ bias,
                                                     float* __restrict__ out) {
    const size_t i = ((size_t)blockIdx.x * 256 + threadIdx.x) * 4;
    float4 a = *(const float4*)(outp + i);
    float4 b = *(const float4*)(outp + (size_t)TT * HD + i);
    float4 bi = *(const float4*)(bias + (i & (HD - 1)));
    float4 o;
    o.x = a.x + b.x + bi.x;
    o.y = a.y + b.y + bi.y;
    o.z = a.z + b.z + bi.z;
    o.w = a.w + b.w + bi.w;
    *(float4*)(out + i) = o;
}

// ---------------------------------------------------------------------------
// Fused causal retention + PV; factorized mask, dbuf P_lds (1 barrier/tile).
// Partials bf16. Grid: (8, 2, 16) = 256 blocks x 512 threads.
// ---------------------------------------------------------------------------
__global__ __launch_bounds__(512) void retention_fused_k(
    const bf16* __restrict__ qr, const bf16* __restrict__ kr,
    const bf16* __restrict__ vT,
    bf16* __restrict__ po0, bf16* __restrict__ po1,
    float* __restrict__ pr0, float* __restrict__ pr1)
{
    __shared__ unsigned short P_lds[2 * 128 * 128];  // 64 KB double-buffered
    __shared__ float rsum_lds[4][128];

    const int tid = threadIdx.x;
    const int lane = tid & 63;
    const int wid = tid >> 6;
    const int wr64 = (wid >> 2) * 64;
    const int wc = wid & 3;
    const int lr = lane & 15;
    const int g = lane >> 4;
    const int lk = g << 3;
    const int pidx = blockIdx.x;
    const int parity = blockIdx.y;
    const int h = blockIdx.z;

    const float decay = logf(1.f - exp2f(-5.f - (float)h));
    bf16* __restrict__ po = parity ? po1 : po0;
    float* __restrict__ pr = parity ? pr1 : pr0;

    const int swzA = (lr & 7) << 3;

    const float bfac0 = __expf(decay * (float)(-(wc * 32 + lr)));
    const float bfac1 = __expf(decay * (float)(-(wc * 32 + 16 + lr)));
    const float astep = __expf(decay * -256.f);

    for (int sec = 0; sec < 2; ++sec) {
        const int qb = sec ? (15 - pidx) : pidx;
        const int qrow0 = qb * 128;

        bf16x8 af[4][4];
#pragma unroll
        for (int mi = 0; mi < 4; ++mi)
#pragma unroll
            for (int ks = 0; ks < 4; ++ks)
                af[mi][ks] = *(const bf16x8*)&qr[(size_t)(qrow0 + wr64 + mi * 16 + lr) * HD +
                                                 h * KD + ks * 32 + lk];

        f32x4 acc_o[4][4] = {};
        float rs[4][4] = {};
        float aexp[4][4];
#pragma unroll
        for (int mi = 0; mi < 4; ++mi)
#pragma unroll
            for (int r = 0; r < 4; ++r) {
                const int row_l = wr64 + mi * 16 + g * 4 + r;
                aexp[mi][r] = __expf(decay * (float)(qrow0 + row_l - parity * 128));
            }

        int pb = 0;
        for (int tb = parity; tb <= qb; tb += 2) {
            const int t0 = tb * 128;

            f32x4 acc_p[4][2] = {};
#pragma unroll
            for (int ks = 0; ks < 4; ++ks) {
                const bf16x8 b0 = *(const bf16x8*)&kr[(size_t)(t0 + wc * 32 + lr) * HD +
                                                      h * KD + ks * 32 + lk];
                const bf16x8 b1 = *(const bf16x8*)&kr[(size_t)(t0 + wc * 32 + 16 + lr) * HD +
                                                      h * KD + ks * 32 + lk];
#pragma unroll
                for (int mi = 0; mi < 4; ++mi) {
                    acc_p[mi][0] = __builtin_amdgcn_mfma_f32_16x16x32_bf16(af[mi][ks], b0, acc_p[mi][0], 0, 0, 0);
                    acc_p[mi][1] = __builtin_amdgcn_mfma_f32_16x16x32_bf16(af[mi][ks], b1, acc_p[mi][1], 0, 0, 0);
                }
            }

#pragma unroll
            for (int mi = 0; mi < 4; ++mi) {
#pragma unroll
                for (int r = 0; r < 4; ++r) {
                    const int rl = g * 4 + r;
                    const int row_l = wr64 + mi * 16 + rl;
                    const int srel = qrow0 + row_l - t0;
                    const float a = aexp[mi][r];
                    const float p0 = (wc * 32 + lr <= srel) ? acc_p[mi][0][r] * a * bfac0 : 0.f;
                    const float p1 = (wc * 32 + 16 + lr <= srel) ? acc_p[mi][1][r] * a * bfac1 : 0.f;
                    const int sw = (rl & 7) << 3;
                    P_lds[pb + row_l * 128 + ((wc * 32 + lr) ^ sw)] = f2bfu(p0);
                    P_lds[pb + row_l * 128 + ((wc * 32 + 16 + lr) ^ sw)] = f2bfu(p1);
                    rs[mi][r] += p0 + p1;
                    aexp[mi][r] = a * astep;
                }
            }
            __syncthreads();

#pragma unroll
            for (int ks2 = 0; ks2 < 4; ++ks2) {
                bf16x8 a2[4], b2[4];
#pragma unroll
                for (int mi = 0; mi < 4; ++mi)
                    a2[mi] = *(const bf16x8*)&P_lds[pb + (wr64 + mi * 16 + lr) * 128 +
                                                    ((ks2 * 32 + lk) ^ swzA)];
#pragma unroll
                for (int ni = 0; ni < 4; ++ni)
                    b2[ni] = *(const bf16x8*)&vT[(size_t)(h * DH + wc * 64 + ni * 16 + lr) * TT +
                                                 t0 + ks2 * 32 + lk];
#pragma unroll
                for (int mi = 0; mi < 4; ++mi)
#pragma unroll
                    for (int ni = 0; ni < 4; ++ni)
                        acc_o[mi][ni] = __builtin_amdgcn_mfma_f32_16x16x32_bf16(a2[mi], b2[ni], acc_o[mi][ni], 0, 0, 0);
            }
            pb ^= 16384;   // no post-PV barrier: next P-write goes to other buffer
        }

#pragma unroll
        for (int mi = 0; mi < 4; ++mi)
#pragma unroll
            for (int r = 0; r < 4; ++r) {
                float v = rs[mi][r];
                v += __shfl_xor(v, 1);
                v += __shfl_xor(v, 2);
                v += __shfl_xor(v, 4);
                v += __shfl_xor(v, 8);
                if (lr == 0) rsum_lds[wc][wr64 + mi * 16 + g * 4 + r] = v;
            }
        __syncthreads();
        if (tid < 128)
            pr[(size_t)h * TT + qrow0 + tid] =
                rsum_lds[0][tid] + rsum_lds[1][tid] + rsum_lds[2][tid] + rsum_lds[3][tid];

#pragma unroll
        for (int mi = 0; mi < 4; ++mi)
#pragma unroll
            for (int ni = 0; ni < 4; ++ni)
#pragma unroll
                for (int r = 0; r < 4; ++r) {
                    const int row_l = wr64 + mi * 16 + g * 4 + r;
                    const int col = wc * 64 + ni * 16 + lr;
                    po[(size_t)(qrow0 + row_l) * VD + h * DH + col] = f2bf(acc_o[mi][ni][r]);
                }
        __syncthreads();
    }
}

// ---------------------------------------------------------------------------
// Combine bf16 parity partials -> scale -> LN(256) -> silu-gate (bf16)
// ---------------------------------------------------------------------------
__global__ __launch_bounds__(256) void ln_gate_k(const bf16* __restrict__ po0,
                                                 const bf16* __restrict__ po1,
                                                 const float* __restrict__ pr0,
                                                 const float* __restrict__ pr1,
                                                 const bf16* __restrict__ sg,
                                                 bf16* __restrict__ gated) {
    const int tid = threadIdx.x;
    const int lane = tid & 63;
    const size_t ridx = (size_t)blockIdx.x * 4 + (tid >> 6);  // = s*16 + h
    const int h = (int)(ridx & 15);
    const int s = (int)(ridx >> 4);

    const float decay = logf(1.f - exp2f(-5.f - (float)h));
    const float Sm = -expm1f(decay * (float)(s + 1)) * exp2f(5.f + (float)h);
    const float norm = rsqrtf(Sm);
    const float raw = pr0[(size_t)h * TT + s] + pr1[(size_t)h * TT + s];
    const float scale = norm / fmaxf(1.f, fabsf(raw * norm));

    unsigned short ua[4], ub[4];
    *(uint2*)ua = *(const uint2*)(po0 + ridx * 256 + lane * 4);
    *(uint2*)ub = *(const uint2*)(po1 + ridx * 256 + lane * 4);
    float vv[4];
#pragma unroll
    for (int i = 0; i < 4; ++i)
        vv[i] = (bf2f(ua[i]) + bf2f(ub[i])) * scale;
    float sm = vv[0] + vv[1] + vv[2] + vv[3];
    float sq = vv[0] * vv[0] + vv[1] * vv[1] + vv[2] * vv[2] + vv[3] * vv[3];
#pragma unroll
    for (int o = 1; o < 64; o <<= 1) {
        sm += __shfl_xor(sm, o);
        sq += __shfl_xor(sq, o);
    }
    const float mu = sm * (1.f / 256.f);
    const float var = sq * (1.f / 256.f) - mu * mu;
    const float rstd = rsqrtf(var + 1e-6f);
    const bf16* sgp = sg + ridx * 256 + lane * 4;
    bf16* gp = gated + ridx * 256 + lane * 4;
    bf16 ob[4];
#pragma unroll
    for (int i = 0; i < 4; ++i)
        ob[i] = f2bf((vv[i] - mu) * rstd * __bfloat162float(sgp[i]));
    *(uint2*)gp = *(const uint2*)ob;
}

// ---------------------------------------------------------------------------
extern "C" void kernel_launch(void* const* d_in, const int* in_sizes, int n_in,
                              void* d_out, int out_size, void* d_ws, size_t ws_size,
                              hipStream_t stream) {
    const float* hidden = (const float*)d_in[0];
    const float* Wq = (const float*)d_in[1];
    const float* bq = (const float*)d_in[2];
    const float* Wk = (const float*)d_in[3];
    const float* bk = (const float*)d_in[4];
    const float* Wv = (const float*)d_in[5];
    const float* bvp = (const float*)d_in[6];
    const float* Wg = (const float*)d_in[7];
    const float* bg = (const float*)d_in[8];
    const float* Wo = (const float*)d_in[9];
    const float* bo = (const float*)d_in[10];
    const float* sinT = (const float*)d_in[11];
    const float* cosT = (const float*)d_in[12];
    float* out = (float*)d_out;

    char* p = (char*)d_ws;
    bf16* hb = (bf16*)p;    p += (size_t)TT * HD * 2;
    bf16* Wcat = (bf16*)p;  p += (size_t)(HD + HD + VD + VD) * HD * 2;
    bf16* WoT = (bf16*)p;   p += (size_t)HD * VD * 2;
    bf16* qr = (bf16*)p;    p += (size_t)TT * HD * 2;
    bf16* kr = (bf16*)p;    p += (size_t)TT * HD * 2;
    bf16* vtmp = (bf16*)p;  p += (size_t)TT * VD * 2;
    bf16* vT = (bf16*)p;    p += (size_t)VD * TT * 2;
    bf16* sg = (bf16*)p;    p += (size_t)TT * VD * 2;
    bf16* po0 = (bf16*)p;   p += (size_t)TT * VD * 2;
    bf16* po1 = (bf16*)p;   p += (size_t)TT * VD * 2;
    float* pr0 = (float*)p; p += (size_t)NH * TT * 4;
    float* pr1 = (float*)p; p += (size_t)NH * TT * 4;
    bf16* gated = (bf16*)p; p += (size_t)TT * VD * 2;
    float* outp = (float*)p; p += (size_t)2 * TT * HD * 4;

    // 1) weight transposes + hidden convert (single launch)
    transpose_all_k<<<8704, 256, 0, stream>>>(Wq, Wk, Wv, Wg, Wo, Wcat, WoT, hidden, hb);

    // 2) fused QKVG projection (8-phase 256x192), V transpose
    gemm_qkvg_k<<<512, 512, 0, stream>>>(hb, Wcat, bq, bk, bvp, bg, sinT, cosT,
                                         qr, kr, vtmp, sg);
    transpose_bf16_k<<<dim3(VD / 64, TT / 64), 256, 0, stream>>>(vtmp, vT);

    // 3) fused causal retention + PV (bf16 partials per kv-parity)
    retention_fused_k<<<dim3(8, 2, NH), 512, 0, stream>>>(qr, kr, vT, po0, po1, pr0, pr1);

    // 4) combine + groupnorm + gate, then output projection (K-split) + combine
    ln_gate_k<<<TT * NH / 4, 256, 0, stream>>>(po0, po1, pr0, pr1, sg, gated);
    gemm_out_k<<<dim3(256, 2), 256, 0, stream>>>(gated, WoT, outp);
    combine_out_k<<<TT * HD / 1024, 256, 0, stream>>>(outp, bo, out);
}